// Round 11
// baseline (436.882 us; speedup 1.0000x reference)
//
#include <hip/hip_runtime.h>
#include <math.h>

typedef __attribute__((ext_vector_type(8))) short bf16x8;
typedef __attribute__((ext_vector_type(4))) float f32x4;
typedef __attribute__((ext_vector_type(2))) float f32x2;

static __device__ __forceinline__ unsigned short f2bf(float f) {
  unsigned u = __float_as_uint(f);
  unsigned r = (u + 0x7FFF + ((u >> 16) & 1)) >> 16; // RNE
  return (unsigned short)r;
}

// Packed f32 VOP3P ops — hipcc scalarizes ext_vector f32 math; force the
// dual-lane instructions (exact same IEEE f32 arithmetic, half the issues).
static __device__ __forceinline__ f32x2 pk_add(f32x2 a, f32x2 b) {
  f32x2 d;
  asm("v_pk_add_f32 %0, %1, %2" : "=v"(d) : "v"(a), "v"(b));
  return d;
}
static __device__ __forceinline__ f32x2 pk_mul(f32x2 a, f32x2 b) {
  f32x2 d;
  asm("v_pk_mul_f32 %0, %1, %2" : "=v"(d) : "v"(a), "v"(b));
  return d;
}
static __device__ __forceinline__ f32x2 pk_fma(f32x2 a, f32x2 b, f32x2 c) {
  f32x2 d;
  asm("v_pk_fma_f32 %0, %1, %2, %3" : "=v"(d) : "v"(a), "v"(b), "v"(c));
  return d;
}

// DPP add: x += lane-permuted x. bound_ctrl=true + bijective ctrl (quad_perm /
// row_half_mirror) lets GCNDPPCombine fold the mov_dpp into v_add_f32_dpp.
#define DPP_ADD(x, ctrl) \
  ((x) + __int_as_float(__builtin_amdgcn_update_dpp(0, __float_as_int(x), (ctrl), 0xf, 0xf, true)))

#define NSHARD 64
#define NEB 256   // edge-chunk blocks for the place pass
#define ECAP 6144 // fixed bucket stride in ebuf (mean fill 4096, sigma 64)

// ---------------- W-prep + single-pass bucket place ----------------

__global__ __launch_bounds__(256) void k_prep(const float* __restrict__ W0, const float* __restrict__ W1,
                                              const float* __restrict__ W2, const float* __restrict__ W3,
                                              const float* __restrict__ W4, const float* __restrict__ W5,
                                              unsigned short* __restrict__ wt,
                                              const int* __restrict__ esrc,
                                              const int* __restrict__ edst,
                                              int* __restrict__ bktcnt,
                                              int2* __restrict__ ebuf, int E, int N) {
  if (blockIdx.x < 384) {
    int gid = blockIdx.x * 256 + threadIdx.x; // 6 * 16384
    int m = gid >> 14;
    int r = gid & 16383;
    int k = r >> 8;
    int n = r & 255;
    const float* W = (m == 0) ? W0 : (m == 1) ? W1 : (m == 2) ? W2
                   : (m == 3) ? W3 : (m == 4) ? W4 : W5;
    wt[(size_t)m * 16384 + n * 64 + k] = f2bf(W[k * 256 + n]);
    return;
  }
  const int b = blockIdx.x - 384;
  const int nbk = (N + 255) >> 8;
  __shared__ int cnt[256], base[256];
  cnt[threadIdx.x] = 0;
  __syncthreads();
  const int chunk = (E + NEB - 1) / NEB;
  const int e0 = b * chunk, e1 = min(e0 + chunk, E);
  for (int e = e0 + threadIdx.x; e < e1; e += 256) atomicAdd(&cnt[edst[e] >> 8], 1);
  __syncthreads();
  if (threadIdx.x < nbk && cnt[threadIdx.x])
    base[threadIdx.x] = atomicAdd(&bktcnt[threadIdx.x], cnt[threadIdx.x]);
  cnt[threadIdx.x] = 0; // reuse as local cursor (own-index only before sync)
  __syncthreads();
  for (int e = e0 + threadIdx.x; e < e1; e += 256) {
    int d = edst[e];
    int bk = d >> 8;
    int p = base[bk] + atomicAdd(&cnt[bk], 1);
    ebuf[(size_t)bk * ECAP + p] = make_int2(d, esrc[e]);
  }
}

// ---------------- pass2 (y=2 of k_mm0): per-bucket CSR finalize, 4-padded ----------------
// Per-node lists padded to %4 (pad slots stay 0 from memset -> safe gather of row 0,
// masked by deg). rowptr packs pos|deg<<22. colb space reserved via global cursor.

static __device__ __forceinline__ void csr_pass2(const int2* __restrict__ ebuf,
                                                 const int* __restrict__ bktcnt,
                                                 int* __restrict__ rowptr,
                                                 int* __restrict__ colb,
                                                 int* __restrict__ ccur,
                                                 int N, char* smem) {
  const int b = blockIdx.x;
  const int nbk = (N + 255) >> 8;
  if (b >= nbk) return;
  int* hist = (int*)smem;          // 256
  int* s = (int*)smem + 256;       // 256 (scan buffer)
  int* sb = (int*)smem + 512;      // 1 (bucket colb-base broadcast)
  const int tid = threadIdx.x;
  const int lo = b * ECAP;
  const int hi = lo + bktcnt[b];
  hist[tid] = 0;
  __syncthreads();
  for (int i = lo + tid; i < hi; i += 256) atomicAdd(&hist[ebuf[i].x & 255], 1);
  __syncthreads();
  int deg = hist[tid];
  int pd = (deg + 3) & ~3;
  s[tid] = pd;
  __syncthreads();
  for (int off = 1; off < 256; off <<= 1) {
    int t = (tid >= off) ? s[tid - off] : 0;
    __syncthreads();
    s[tid] += t;
    __syncthreads();
  }
  if (tid == 255) sb[0] = atomicAdd(ccur, s[255]);
  __syncthreads();
  int pos = sb[0] + s[tid] - pd; // exclusive prefix of padded degrees
  int node = (b << 8) + tid;
  if (node < N) rowptr[node] = (int)((unsigned)pos | ((unsigned)deg << 22));
  hist[tid] = pos; // reuse as global cursor
  __syncthreads();
  for (int i = lo + tid; i < hi; i += 256) {
    int2 e = ebuf[i];
    int p = atomicAdd(&hist[e.x & 255], 1);
    colb[p] = e.y << 8; // byte offset into fp8 rows (256 fp8 = 256 B)
  }
}

// ---------------- MFMA dual GEMM + fused BN/GELU/residual producer (shared body) ----
// Gather copies (xlb/xrb) stored as OCP fp8 e4m3 (256 B/row) — consumed only by
// k_gat. Single-bf16 GEMM (outputs fp8-quantized anyway; hout keeps f32 quality).

static __device__ __forceinline__ void mm_gemm(const float* __restrict__ src,
                                               const float* __restrict__ bnsums,
                                               const float* __restrict__ g,
                                               const float* __restrict__ be,
                                               const float* __restrict__ resid,
                                               float* __restrict__ hout,
                                               const unsigned short* __restrict__ wt,
                                               unsigned char* __restrict__ xlb,
                                               unsigned char* __restrict__ xrb,
                                               int N, int ntiles, float inv_n,
                                               char* smem) {
  unsigned short* Bs = (unsigned short*)smem;           // 256*64 shorts, swizzled
  unsigned short* Ah = (unsigned short*)(smem + 32768); // 32*64
  const int t = threadIdx.x;
  const unsigned short* wb = wt + (blockIdx.y ? 16384 : 0);
  unsigned char* dst = blockIdx.y ? xrb : xlb;

  const int wave = t >> 6, lane = t & 63;
  const int rw = (wave & 1) * 16, cw = (wave >> 1) * 128;
  const int m15 = lane & 15, quad = lane >> 4;
  const int arow = t >> 3, ac0 = (t & 7) * 8;
  const int aoff = arow * 64 + (((t & 7) ^ (arow & 7)) << 3); // swizzled A slot

  float scale[8], shift[8];
  if (bnsums) {
    float* stat = (float*)smem; // overlay: consumed before Bs fill
    if (t < 128) {
      float a = 0.f;
#pragma unroll
      for (int sd = 0; sd < NSHARD; ++sd) a += bnsums[sd * 128 + t];
      stat[t] = a;
    }
    __syncthreads();
#pragma unroll
    for (int i = 0; i < 8; ++i) {
      int c = ac0 + i;
      float mu = stat[c] * inv_n;
      float var = stat[64 + c] * inv_n - mu * mu;
      float rs = rsqrtf(var + 1e-5f) * g[c];
      scale[i] = rs;
      shift[i] = be[c] - mu * rs;
    }
    __syncthreads(); // stat reads done before Bs fill overwrites
  }

#pragma unroll
  for (int j = 0; j < 8; ++j) {
    int cidx = t + 256 * j;
    int n = cidx >> 3, gg = cidx & 7;
    *(bf16x8*)&Bs[n * 64 + (((gg ^ ((n >> 3) & 7))) << 3)] =
        *(const bf16x8*)(wb + (size_t)n * 64 + gg * 8);
  }

  const bool wr_h = (hout != nullptr) && (blockIdx.y == 0);
  const int gstride = gridDim.x;

  float4 a0, a1, rv0, rv1;
  auto loadA = [&](int tl, float4& x0, float4& x1, float4& r0v, float4& r1v) {
    x0 = make_float4(0.f, 0.f, 0.f, 0.f);
    x1 = make_float4(0.f, 0.f, 0.f, 0.f);
    r0v = make_float4(0.f, 0.f, 0.f, 0.f);
    r1v = make_float4(0.f, 0.f, 0.f, 0.f);
    int gr = tl * 32 + arow;
    if (tl < ntiles && gr < N) {
      x0 = *(const float4*)(src + (size_t)gr * 64 + ac0);
      x1 = *(const float4*)(src + (size_t)gr * 64 + ac0 + 4);
      if (resid) {
        r0v = *(const float4*)(resid + (size_t)gr * 64 + ac0);
        r1v = *(const float4*)(resid + (size_t)gr * 64 + ac0 + 4);
      }
    }
  };
  loadA(blockIdx.x, a0, a1, rv0, rv1);

  for (int tile = blockIdx.x; tile < ntiles; tile += gstride) {
    int r0 = tile * 32;
    int gr = r0 + arow;
    {
      float vs[8] = {a0.x, a0.y, a0.z, a0.w, a1.x, a1.y, a1.z, a1.w};
      if (bnsums) {
        float rv[8] = {rv0.x, rv0.y, rv0.z, rv0.w, rv1.x, rv1.y, rv1.z, rv1.w};
#pragma unroll
        for (int i = 0; i < 8; ++i) {
          float v = fmaf(vs[i], scale[i], shift[i]);
          float ge = 0.5f * v * (1.f + erff(v * 0.70710678118654752f));
          vs[i] = ge + rv[i];
        }
        if (wr_h && gr < N) {
          float4 o0 = {vs[0], vs[1], vs[2], vs[3]};
          float4 o1 = {vs[4], vs[5], vs[6], vs[7]};
          *(float4*)(hout + (size_t)gr * 64 + ac0) = o0;
          *(float4*)(hout + (size_t)gr * 64 + ac0 + 4) = o1;
        }
      }
      bf16x8 hi8;
#pragma unroll
      for (int i = 0; i < 8; ++i) hi8[i] = (short)f2bf(vs[i]);
      *(bf16x8*)&Ah[aoff] = hi8;
    }
    __syncthreads();

    // software pipeline: issue next tile's A loads under MFMA + epilogue
    loadA(tile + gstride, a0, a1, rv0, rv1);

    f32x4 acc[8];
#pragma unroll
    for (int s = 0; s < 8; ++s) acc[s] = (f32x4){0.f, 0.f, 0.f, 0.f};
    const int xq = m15 & 7;
#pragma unroll
    for (int kk = 0; kk < 64; kk += 32) {
      const int ga = (((kk >> 3) + quad) ^ xq) << 3;
      bf16x8 ah = *(const bf16x8*)&Ah[(rw + m15) * 64 + ga];
#pragma unroll
      for (int s = 0; s < 8; ++s) {
        // B row cw + m15*8 + s -> acc[s] holds output column cw + m15*8 + s
        bf16x8 b = *(const bf16x8*)&Bs[(cw + m15 * 8 + s) * 64 + ga];
        acc[s] = __builtin_amdgcn_mfma_f32_16x16x32_bf16(ah, b, acc[s], 0, 0, 0);
      }
    }
#pragma unroll
    for (int r = 0; r < 4; ++r) {
      int row_g = r0 + rw + quad * 4 + r;
      if (row_g < N) {
        int w0 = __builtin_amdgcn_cvt_pk_fp8_f32(acc[0][r], acc[1][r], 0, false);
        w0 = __builtin_amdgcn_cvt_pk_fp8_f32(acc[2][r], acc[3][r], w0, true);
        int w1 = __builtin_amdgcn_cvt_pk_fp8_f32(acc[4][r], acc[5][r], 0, false);
        w1 = __builtin_amdgcn_cvt_pk_fp8_f32(acc[6][r], acc[7][r], w1, true);
        uint2 o = {(unsigned)w0, (unsigned)w1};
        *(uint2*)(dst + (size_t)row_g * 256 + cw + m15 * 8) = o;
      }
    }
    __syncthreads();
  }
}

__global__ __launch_bounds__(256, 4) void k_mm0(const float* __restrict__ src,
                                                const unsigned short* __restrict__ wt,
                                                unsigned char* __restrict__ xlb,
                                                unsigned char* __restrict__ xrb,
                                                const int2* __restrict__ ebuf,
                                                const int* __restrict__ bktcnt,
                                                int* __restrict__ rowptr,
                                                int* __restrict__ colb,
                                                int* __restrict__ ccur,
                                                int N, int ntiles) {
  __shared__ __align__(16) char smem[36864];
  if (blockIdx.y == 2) {
    csr_pass2(ebuf, bktcnt, rowptr, colb, ccur, N, smem);
    return;
  }
  mm_gemm(src, nullptr, nullptr, nullptr, nullptr, nullptr, wt, xlb, xrb, N, ntiles, 0.f, smem);
}

__global__ __launch_bounds__(256, 4) void k_mm1(const float* __restrict__ src,
                                                const float* __restrict__ bnsums,
                                                const float* __restrict__ g,
                                                const float* __restrict__ be,
                                                float* __restrict__ hout,
                                                const unsigned short* __restrict__ wt,
                                                unsigned char* __restrict__ xlb,
                                                unsigned char* __restrict__ xrb,
                                                int N, int ntiles, float inv_n) {
  __shared__ __align__(16) char smem[36864];
  mm_gemm(src, bnsums, g, be, nullptr, hout, wt, xlb, xrb, N, ntiles, inv_n, smem);
}

__global__ __launch_bounds__(256, 4) void k_mm2(const float* __restrict__ src,
                                                const float* __restrict__ bnsums,
                                                const float* __restrict__ g,
                                                const float* __restrict__ be,
                                                const float* __restrict__ resid,
                                                float* __restrict__ hout,
                                                const unsigned short* __restrict__ wt,
                                                unsigned char* __restrict__ xlb,
                                                unsigned char* __restrict__ xrb,
                                                int N, int ntiles, float inv_n) {
  __shared__ __align__(16) char smem[36864];
  mm_gemm(src, bnsums, g, be, resid, hout, wt, xlb, xrb, N, ntiles, inv_n, smem);
}

// ---------------- GATv2: 2-edges-per-wave, fp8 gather rows, packed-f32 math ----
// Lanes 0-31 carry edge A, lanes 32-63 edge B. Channel math uses explicit
// v_pk_*_f32 (inline asm) — hipcc scalarizes ext_vector f32 ops otherwise.
// Independent accumulator sets per edge-pair slot break serial fma chains.

static __device__ __forceinline__ void gat_body(const unsigned char* __restrict__ xlb,
                                                const unsigned char* __restrict__ xrb,
                                                const float* __restrict__ att,
                                                const float* __restrict__ bias,
                                                const int* __restrict__ rowptr,
                                                const int* __restrict__ colb,
                                                float* __restrict__ out,
                                                float* __restrict__ bnsums, int N) {
  __shared__ float sres[4][64];
  const int lane = threadIdx.x & 63;
  const int wv = threadIdx.x >> 6;
  const int half = lane >> 5; // which edge of the pair this lane serves
  const int l5 = lane & 31;
  const int node0 = blockIdx.x * 4 + wv;
  const bool valid = node0 < N;
  const int node = __builtin_amdgcn_readfirstlane(valid ? node0 : 0); // wave-uniform
  const int rp = rowptr[node];
  const int beg = rp & 0x3FFFFF;
  const int deg = (int)(((unsigned)rp) >> 22);
  const int end = valid ? beg + deg : beg;

  const unsigned char* xl = xlb; // wave-uniform base -> SADDR form
  const unsigned lb = (unsigned)l5 * 8u;

  auto sel = [&](int a, int b) { return (unsigned)(half ? b : a); };

  int4 c0 = *(const int4*)(colb + beg);     // edges 0..3 (16B-aligned: beg%4==0)
  int4 c1 = *(const int4*)(colb + beg + 4); // edges 4..7
  const unsigned self_off = (unsigned)(node << 8);
  uint2 vbs = *(const uint2*)(xl + self_off + lb);
  uint2 pd0 = *(const uint2*)(xl + (sel(c0.x, c0.y) + lb));
  uint2 pd1 = *(const uint2*)(xl + (sel(c0.z, c0.w) + lb));
  uint2 pt0 = *(const uint2*)(xl + (sel(c1.x, c1.y) + lb));
  uint2 pt1 = *(const uint2*)(xl + (sel(c1.z, c1.w) + lb));
  int4 cn = *(const int4*)(colb + beg + 8); // offsets for edges 8..11

  float4 aa = *(const float4*)(att + l5 * 8);
  float4 ab = *(const float4*)(att + l5 * 8 + 4);
  const float LOG2E = 1.4426950408889634f;
  const f32x2 a01 = {aa.x * LOG2E, aa.y * LOG2E};
  const f32x2 a23 = {aa.z * LOG2E, aa.w * LOG2E};
  const f32x2 a45 = {ab.x * LOG2E, ab.y * LOG2E};
  const f32x2 a67 = {ab.z * LOG2E, ab.w * LOG2E};
  const f32x2 c02 = {0.2f, 0.2f};
  uint2 xru = *(const uint2*)(xrb + self_off + lb);
  const f32x2 xr01 = __builtin_amdgcn_cvt_pk_f32_fp8((int)xru.x, false);
  const f32x2 xr23 = __builtin_amdgcn_cvt_pk_f32_fp8((int)xru.x, true);
  const f32x2 xr45 = __builtin_amdgcn_cvt_pk_f32_fp8((int)xru.y, false);
  const f32x2 xr67 = __builtin_amdgcn_cvt_pk_f32_fp8((int)xru.y, true);

  // score over 8 channels/lane, reduced across the 8-lane head group (both
  // halves reduce their own edge). Returns per-(head,edge) score; also yields
  // the converted channel values for the accumulation.
  auto score = [&](uint2 vb, f32x2& v01, f32x2& v23, f32x2& v45, f32x2& v67) -> float {
    v01 = __builtin_amdgcn_cvt_pk_f32_fp8((int)vb.x, false);
    v23 = __builtin_amdgcn_cvt_pk_f32_fp8((int)vb.x, true);
    v45 = __builtin_amdgcn_cvt_pk_f32_fp8((int)vb.y, false);
    v67 = __builtin_amdgcn_cvt_pk_f32_fp8((int)vb.y, true);
    f32x2 s01 = pk_add(v01, xr01);
    f32x2 s23 = pk_add(v23, xr23);
    f32x2 s45 = pk_add(v45, xr45);
    f32x2 s67 = pk_add(v67, xr67);
    s01 = __builtin_elementwise_max(s01, pk_mul(s01, c02));
    s23 = __builtin_elementwise_max(s23, pk_mul(s23, c02));
    s45 = __builtin_elementwise_max(s45, pk_mul(s45, c02));
    s67 = __builtin_elementwise_max(s67, pk_mul(s67, c02));
    f32x2 q = pk_mul(s01, a01);
    q = pk_fma(s23, a23, q);
    q = pk_fma(s45, a45, q);
    q = pk_fma(s67, a67, q);
    float p = q.x + q.y;
    p = DPP_ADD(p, 0xB1);  // quad_perm [1,0,3,2]
    p = DPP_ADD(p, 0x4E);  // quad_perm [2,3,0,1]
    p = DPP_ADD(p, 0x141); // row_half_mirror -> 8-lane (head) group sum
    return p;
  };

  f32x2 sv01, sv23, sv45, sv67;
  const float m = score(vbs, sv01, sv23, sv45, sv67); // self score (identical in both halves)

  const float hsel = half ? 0.f : 1.f; // self counted once (half 0)
  float lsumA = hsel, lsumB = 0.f;
  const f32x2 hs2 = {hsel, hsel};
  f32x2 oA01 = pk_mul(sv01, hs2), oA23 = pk_mul(sv23, hs2);
  f32x2 oA45 = pk_mul(sv45, hs2), oA67 = pk_mul(sv67, hs2);
  f32x2 oB01 = {0.f, 0.f}, oB23 = {0.f, 0.f}, oB45 = {0.f, 0.f}, oB67 = {0.f, 0.f};

  auto proc = [&](uint2 vb, int ebase, float& lsum,
                  f32x2& o01, f32x2& o23, f32x2& o45, f32x2& o67) {
    f32x2 v01, v23, v45, v67;
    float p = score(vb, v01, v23, v45, v67);
    float w = __builtin_amdgcn_exp2f(fminf(p - m, 126.f));
    w = (ebase + half < end) ? w : 0.f;
    lsum += w;
    f32x2 w2 = {w, w};
    o01 = pk_fma(w2, v01, o01);
    o23 = pk_fma(w2, v23, o23);
    o45 = pk_fma(w2, v45, o45);
    o67 = pk_fma(w2, v67, o67);
  };

  for (int e = beg; e < end; e += 4) {
    uint2 pu0 = *(const uint2*)(xl + (sel(cn.x, cn.y) + lb));
    uint2 pu1 = *(const uint2*)(xl + (sel(cn.z, cn.w) + lb));
    cn = *(const int4*)(colb + e + 12);
    proc(pd0, e, lsumA, oA01, oA23, oA45, oA67);
    proc(pd1, e + 2, lsumB, oB01, oB23, oB45, oB67);
    pd0 = pt0; pd1 = pt1;
    pt0 = pu0; pt1 = pu1;
  }

  // merge A/B accumulator sets, then per-head denominator across edge halves
  float lsum = lsumA + lsumB;
  f32x2 o01 = pk_add(oA01, oB01), o23 = pk_add(oA23, oB23);
  f32x2 o45 = pk_add(oA45, oB45), o67 = pk_add(oA67, oB67);
  lsum += __shfl_xor(lsum, 32, 64);
  float inv = __builtin_amdgcn_rcpf(lsum);
  float r[8] = {o01.x * inv, o01.y * inv, o23.x * inv, o23.y * inv,
                o45.x * inv, o45.y * inv, o67.x * inv, o67.y * inv};
#pragma unroll
  for (int j = 0; j < 8; ++j) {
    r[j] += __shfl_xor(r[j], 8, 64);  // head pairs
    r[j] += __shfl_xor(r[j], 16, 64); // all 4 heads
    r[j] += __shfl_xor(r[j], 32, 64); // edge halves
  }
  if (lane < 8) {
    float4 res0 = {0.f, 0.f, 0.f, 0.f}, res1 = {0.f, 0.f, 0.f, 0.f};
    if (valid) {
      float4 b0 = *(const float4*)(bias + lane * 8);
      float4 b1 = *(const float4*)(bias + lane * 8 + 4);
      res0.x = 0.25f * r[0] + b0.x;
      res0.y = 0.25f * r[1] + b0.y;
      res0.z = 0.25f * r[2] + b0.z;
      res0.w = 0.25f * r[3] + b0.w;
      res1.x = 0.25f * r[4] + b1.x;
      res1.y = 0.25f * r[5] + b1.y;
      res1.z = 0.25f * r[6] + b1.z;
      res1.w = 0.25f * r[7] + b1.w;
      *(float4*)(out + (size_t)node * 64 + lane * 8) = res0;
      *(float4*)(out + (size_t)node * 64 + lane * 8 + 4) = res1;
    }
    *(float4*)&sres[wv][lane * 8] = res0;
    *(float4*)&sres[wv][lane * 8 + 4] = res1;
  }
  __syncthreads();
  if (threadIdx.x < 64) {
    int c = threadIdx.x;
    float s0 = sres[0][c], s1 = sres[1][c], s2 = sres[2][c], s3 = sres[3][c];
    float* bs = bnsums + (size_t)(blockIdx.x & (NSHARD - 1)) * 128;
    atomicAdd(&bs[c], s0 + s1 + s2 + s3);
    atomicAdd(&bs[64 + c], s0 * s0 + s1 * s1 + s2 * s2 + s3 * s3);
  }
}

__global__ __launch_bounds__(256) void k_gat0(const unsigned char* __restrict__ xlb,
                                              const unsigned char* __restrict__ xrb,
                                              const float* __restrict__ att,
                                              const float* __restrict__ bias,
                                              const int* __restrict__ rowptr,
                                              const int* __restrict__ colb,
                                              float* __restrict__ out,
                                              float* __restrict__ bnsums, int N) {
  gat_body(xlb, xrb, att, bias, rowptr, colb, out, bnsums, N);
}
__global__ __launch_bounds__(256) void k_gat1(const unsigned char* __restrict__ xlb,
                                              const unsigned char* __restrict__ xrb,
                                              const float* __restrict__ att,
                                              const float* __restrict__ bias,
                                              const int* __restrict__ rowptr,
                                              const int* __restrict__ colb,
                                              float* __restrict__ out,
                                              float* __restrict__ bnsums, int N) {
  gat_body(xlb, xrb, att, bias, rowptr, colb, out, bnsums, N);
}
__global__ __launch_bounds__(256) void k_gat2(const unsigned char* __restrict__ xlb,
                                              const unsigned char* __restrict__ xrb,
                                              const float* __restrict__ att,
                                              const float* __restrict__ bias,
                                              const int* __restrict__ rowptr,
                                              const int* __restrict__ colb,
                                              float* __restrict__ out,
                                              float* __restrict__ bnsums, int N) {
  gat_body(xlb, xrb, att, bias, rowptr, colb, out, bnsums, N);
}

// ---------------- final: collapse shards -> BN+GELU+residual -> run-batched pool ----------------

__global__ __launch_bounds__(256) void k_bn_pool(const float* __restrict__ gat,
                                                 const float* __restrict__ bnsums,
                                                 const float* __restrict__ g,
                                                 const float* __restrict__ be,
                                                 const float* __restrict__ resid,
                                                 const int* __restrict__ batch,
                                                 float* __restrict__ pool,
                                                 int N, float inv_n) {
  __shared__ float sc[64], sh[64];
  if (threadIdx.x < 64) {
    int c = threadIdx.x;
    float s = 0.f, q = 0.f;
    for (int sd = 0; sd < NSHARD; ++sd) {
      s += bnsums[sd * 128 + c];
      q += bnsums[sd * 128 + 64 + c];
    }
    float mu = s * inv_n;
    float var = q * inv_n - mu * mu;
    float rs = rsqrtf(var + 1e-5f) * g[c];
    sc[c] = rs;
    sh[c] = be[c] - mu * rs;
  }
  __syncthreads();
  const int c = threadIdx.x & 63;
  const int wv = threadIdx.x >> 6;
  int n0 = (blockIdx.x * 4 + wv) * 32;
  if (n0 >= N) return;
  int n1 = min(n0 + 32, N);
  int curg = batch[n0]; // wave-uniform (batch sorted)
  float acc = 0.f;
  for (int n = n0; n < n1; ++n) {
    int b = batch[n];
    if (b != curg) {
      atomicAdd(&pool[(size_t)curg * 64 + c], acc);
      acc = 0.f;
      curg = b;
    }
    float v = fmaf(gat[(size_t)n * 64 + c], sc[c], sh[c]);
    float ge = 0.5f * v * (1.f + erff(v * 0.70710678118654752f));
    acc += ge + resid[(size_t)n * 64 + c];
  }
  atomicAdd(&pool[(size_t)curg * 64 + c], acc);
}

// ---------------- heads ----------------

__global__ void k_head(const float* __restrict__ pool, const float* __restrict__ Wmu,
                       const float* __restrict__ bmu, const float* __restrict__ Wlv,
                       const float* __restrict__ blv, float* __restrict__ out, int G) {
  int g = blockIdx.x;
  int c = threadIdx.x; // 64 threads
  __shared__ float row[64];
  row[c] = pool[(size_t)g * 64 + c];
  __syncthreads();
  float am = 0.f, al = 0.f;
  for (int k = 0; k < 64; ++k) {
    float r = row[k];
    am = fmaf(r, Wmu[k * 64 + c], am);
    al = fmaf(r, Wlv[k * 64 + c], al);
  }
  out[(size_t)g * 64 + c] = am + bmu[c];
  out[(size_t)G * 64 + (size_t)g * 64 + c] = al + blv[c];
}

// ---------------- launch ----------------

extern "C" void kernel_launch(void* const* d_in, const int* in_sizes, int n_in,
                              void* d_out, int out_size, void* d_ws, size_t ws_size,
                              hipStream_t stream) {
  const float* x    = (const float*)d_in[0];
  const int* esrc   = (const int*)d_in[1];
  const int* edst   = (const int*)d_in[2];
  const int* batch  = (const int*)d_in[3];
  const float* Wl[3]  = {(const float*)d_in[5],  (const float*)d_in[11], (const float*)d_in[17]};
  const float* Wr[3]  = {(const float*)d_in[6],  (const float*)d_in[12], (const float*)d_in[18]};
  const float* att[3] = {(const float*)d_in[7],  (const float*)d_in[13], (const float*)d_in[19]};
  const float* bia[3] = {(const float*)d_in[8],  (const float*)d_in[14], (const float*)d_in[20]};
  const float* gam[3] = {(const float*)d_in[9],  (const float*)d_in[15], (const float*)d_in[21]};
  const float* bet[3] = {(const float*)d_in[10], (const float*)d_in[16], (const float*)d_in[22]};
  const float* Wmu = (const float*)d_in[23];
  const float* bmu = (const float*)d_in[24];
  const float* Wlv = (const float*)d_in[25];
  const float* blv = (const float*)d_in[26];
  float* out = (float*)d_out;

  const int N = in_sizes[0] / 64;
  const int E = in_sizes[1];
  const int G = out_size / 128;
  const int nbk = (N + 255) / 256;

  char* p = (char*)d_ws;
  auto alloc = [&](size_t bytes) -> void* {
    void* r = (void*)p;
    p += (bytes + 255) & ~(size_t)255;
    return r;
  };
  // zero-init region first (one memset: bktcnt + bnsums + pool + ccur + colb)
  int*   bktcnt  = (int*)alloc(256 * 4);
  float* bnsums  = (float*)alloc(3 * NSHARD * 128 * 4);
  float* pool    = (float*)alloc((size_t)G * 64 * 4);
  int*   ccur    = (int*)alloc(256);
  int*   colb    = (int*)alloc(((size_t)E + 3 * (size_t)N + 64) * 4); // 4-padded rows + zero tail
  char*  zend    = p;
  unsigned char* xlb = (unsigned char*)alloc((size_t)N * 256);
  unsigned char* xrb = (unsigned char*)alloc((size_t)N * 256);
  float* hA     = (float*)alloc((size_t)N * 64 * 4);
  float* hB     = (float*)alloc((size_t)N * 64 * 4);
  float* gat    = (float*)alloc((size_t)N * 64 * 4);
  int*   rowptr = (int*)alloc((size_t)(N + 1) * 4);
  int2*  ebuf   = (int2*)alloc((size_t)nbk * ECAP * 8);
  unsigned short* wt = (unsigned short*)alloc(6 * 16384 * 2);

  const int nbGat = (N + 3) / 4;
  const int ntiles = (N + 31) / 32;
  const float inv_n = 1.f / (float)N;

  hipMemsetAsync(bktcnt, 0, (size_t)(zend - (char*)bktcnt), stream);

  // ---- CSR build: W-prep + single-pass bucket place (fused) ----
  k_prep<<<384 + NEB, 256, 0, stream>>>(Wl[0], Wr[0], Wl[1], Wr[1], Wl[2], Wr[2], wt,
                                        esrc, edst, bktcnt, ebuf, E, N);

  float* bns0 = bnsums;
  float* bns1 = bnsums + NSHARD * 128;
  float* bns2 = bnsums + 2 * NSHARD * 128;

  // ---- layer 0 (y=2 partition finalizes CSR concurrently with the GEMM) ----
  k_mm0<<<dim3(512, 3), 256, 0, stream>>>(x, wt, xlb, xrb, ebuf, bktcnt, rowptr, colb,
                                          ccur, N, ntiles);
  k_gat0<<<nbGat, 256, 0, stream>>>(xlb, xrb, att[0], bia[0], rowptr, colb, gat, bns0, N);
  // ---- layer 1 (applies h0 = gelu(bn0(gat0))) ----
  k_mm1<<<dim3(512, 2), 256, 0, stream>>>(gat, bns0, gam[0], bet[0], hA,
                                          wt + 2 * 16384, xlb, xrb, N, ntiles, inv_n);
  k_gat1<<<nbGat, 256, 0, stream>>>(xlb, xrb, att[1], bia[1], rowptr, colb, gat, bns1, N);
  // ---- layer 2 (applies h1 = gelu(bn1(gat1)) + h0) ----
  k_mm2<<<dim3(512, 2), 256, 0, stream>>>(gat, bns1, gam[1], bet[1], hA, hB,
                                          wt + 4 * 16384, xlb, xrb, N, ntiles, inv_n);
  k_gat2<<<nbGat, 256, 0, stream>>>(xlb, xrb, att[2], bia[2], rowptr, colb, gat, bns2, N);
  // ---- final: h2 = gelu(bn2(gat2)) + h1 -> pool ----
  k_bn_pool<<<(N + 127) / 128, 256, 0, stream>>>(gat, bns2, gam[2], bet[2], hB, batch, pool,
                                                 N, inv_n);
  k_head<<<G, 64, 0, stream>>>(pool, Wmu, bmu, Wlv, blv, out, G);
}

// Round 12
// 370.922 us; speedup vs baseline: 1.1778x; 1.1778x over previous
//
#include <hip/hip_runtime.h>
#include <math.h>

typedef __attribute__((ext_vector_type(8))) short bf16x8;
typedef __attribute__((ext_vector_type(4))) float f32x4;
typedef __attribute__((ext_vector_type(2))) float f32x2;

static __device__ __forceinline__ unsigned short f2bf(float f) {
  unsigned u = __float_as_uint(f);
  unsigned r = (u + 0x7FFF + ((u >> 16) & 1)) >> 16; // RNE
  return (unsigned short)r;
}

// DPP add: x += lane-permuted x. old = src (not literal 0): all ctrl patterns
// used are bijective so old is irrelevant, but old=0 can force a v_mov of the
// literal; old=src lets GCNDPPCombine fold to a single v_add_f32_dpp.
#define DPP_ADD(x, ctrl) \
  ((x) + __int_as_float(__builtin_amdgcn_update_dpp(__float_as_int(x), __float_as_int(x), (ctrl), 0xf, 0xf, false)))

#define NSHARD 64
#define NEB 256   // edge-chunk blocks for the place pass
#define ECAP 6144 // fixed bucket stride in ebuf (mean fill 4096, sigma 64)

// ---------------- W-prep + single-pass bucket place ----------------

__global__ __launch_bounds__(256) void k_prep(const float* __restrict__ W0, const float* __restrict__ W1,
                                              const float* __restrict__ W2, const float* __restrict__ W3,
                                              const float* __restrict__ W4, const float* __restrict__ W5,
                                              unsigned short* __restrict__ wt,
                                              const int* __restrict__ esrc,
                                              const int* __restrict__ edst,
                                              int* __restrict__ bktcnt,
                                              int2* __restrict__ ebuf, int E, int N) {
  if (blockIdx.x < 384) {
    int gid = blockIdx.x * 256 + threadIdx.x; // 6 * 16384
    int m = gid >> 14;
    int r = gid & 16383;
    int k = r >> 8;
    int n = r & 255;
    const float* W = (m == 0) ? W0 : (m == 1) ? W1 : (m == 2) ? W2
                   : (m == 3) ? W3 : (m == 4) ? W4 : W5;
    wt[(size_t)m * 16384 + n * 64 + k] = f2bf(W[k * 256 + n]);
    return;
  }
  const int b = blockIdx.x - 384;
  const int nbk = (N + 255) >> 8;
  __shared__ int cnt[256], base[256];
  cnt[threadIdx.x] = 0;
  __syncthreads();
  const int chunk = (E + NEB - 1) / NEB;
  const int e0 = b * chunk, e1 = min(e0 + chunk, E);
  for (int e = e0 + threadIdx.x; e < e1; e += 256) atomicAdd(&cnt[edst[e] >> 8], 1);
  __syncthreads();
  if (threadIdx.x < nbk && cnt[threadIdx.x])
    base[threadIdx.x] = atomicAdd(&bktcnt[threadIdx.x], cnt[threadIdx.x]);
  cnt[threadIdx.x] = 0; // reuse as local cursor (own-index only before sync)
  __syncthreads();
  for (int e = e0 + threadIdx.x; e < e1; e += 256) {
    int d = edst[e];
    int bk = d >> 8;
    int p = base[bk] + atomicAdd(&cnt[bk], 1);
    ebuf[(size_t)bk * ECAP + p] = make_int2(d, esrc[e]);
  }
}

// ---------------- pass2 (y=2 of k_mm0): per-bucket CSR finalize, 4-padded ----------------
// Per-node lists padded to %4 (pad slots stay 0 from memset -> safe gather of row 0,
// masked by deg). rowptr packs pos|deg<<22. colb space reserved via global cursor.

static __device__ __forceinline__ void csr_pass2(const int2* __restrict__ ebuf,
                                                 const int* __restrict__ bktcnt,
                                                 int* __restrict__ rowptr,
                                                 int* __restrict__ colb,
                                                 int* __restrict__ ccur,
                                                 int N, char* smem) {
  const int b = blockIdx.x;
  const int nbk = (N + 255) >> 8;
  if (b >= nbk) return;
  int* hist = (int*)smem;          // 256
  int* s = (int*)smem + 256;       // 256 (scan buffer)
  int* sb = (int*)smem + 512;      // 1 (bucket colb-base broadcast)
  const int tid = threadIdx.x;
  const int lo = b * ECAP;
  const int hi = lo + bktcnt[b];
  hist[tid] = 0;
  __syncthreads();
  for (int i = lo + tid; i < hi; i += 256) atomicAdd(&hist[ebuf[i].x & 255], 1);
  __syncthreads();
  int deg = hist[tid];
  int pd = (deg + 3) & ~3;
  s[tid] = pd;
  __syncthreads();
  for (int off = 1; off < 256; off <<= 1) {
    int t = (tid >= off) ? s[tid - off] : 0;
    __syncthreads();
    s[tid] += t;
    __syncthreads();
  }
  if (tid == 255) sb[0] = atomicAdd(ccur, s[255]);
  __syncthreads();
  int pos = sb[0] + s[tid] - pd; // exclusive prefix of padded degrees
  int node = (b << 8) + tid;
  if (node < N) rowptr[node] = (int)((unsigned)pos | ((unsigned)deg << 22));
  hist[tid] = pos; // reuse as global cursor
  __syncthreads();
  for (int i = lo + tid; i < hi; i += 256) {
    int2 e = ebuf[i];
    int p = atomicAdd(&hist[e.x & 255], 1);
    colb[p] = e.y << 8; // byte offset into fp8 rows (256 fp8 = 256 B)
  }
}

// ---------------- MFMA dual GEMM + fused BN/GELU/residual producer (shared body) ----
// Gather copies (xlb/xrb) stored as OCP fp8 e4m3 (256 B/row) — consumed only by
// k_gat. Single-bf16 GEMM (outputs fp8-quantized anyway; hout keeps f32 quality).

static __device__ __forceinline__ void mm_gemm(const float* __restrict__ src,
                                               const float* __restrict__ bnsums,
                                               const float* __restrict__ g,
                                               const float* __restrict__ be,
                                               const float* __restrict__ resid,
                                               float* __restrict__ hout,
                                               const unsigned short* __restrict__ wt,
                                               unsigned char* __restrict__ xlb,
                                               unsigned char* __restrict__ xrb,
                                               int N, int ntiles, float inv_n,
                                               char* smem) {
  unsigned short* Bs = (unsigned short*)smem;           // 256*64 shorts, swizzled
  unsigned short* Ah = (unsigned short*)(smem + 32768); // 32*64
  const int t = threadIdx.x;
  const unsigned short* wb = wt + (blockIdx.y ? 16384 : 0);
  unsigned char* dst = blockIdx.y ? xrb : xlb;

  const int wave = t >> 6, lane = t & 63;
  const int rw = (wave & 1) * 16, cw = (wave >> 1) * 128;
  const int m15 = lane & 15, quad = lane >> 4;
  const int arow = t >> 3, ac0 = (t & 7) * 8;
  const int aoff = arow * 64 + (((t & 7) ^ (arow & 7)) << 3); // swizzled A slot

  float scale[8], shift[8];
  if (bnsums) {
    float* stat = (float*)smem; // overlay: consumed before Bs fill
    if (t < 128) {
      float a = 0.f;
#pragma unroll
      for (int sd = 0; sd < NSHARD; ++sd) a += bnsums[sd * 128 + t];
      stat[t] = a;
    }
    __syncthreads();
#pragma unroll
    for (int i = 0; i < 8; ++i) {
      int c = ac0 + i;
      float mu = stat[c] * inv_n;
      float var = stat[64 + c] * inv_n - mu * mu;
      float rs = rsqrtf(var + 1e-5f) * g[c];
      scale[i] = rs;
      shift[i] = be[c] - mu * rs;
    }
    __syncthreads(); // stat reads done before Bs fill overwrites
  }

#pragma unroll
  for (int j = 0; j < 8; ++j) {
    int cidx = t + 256 * j;
    int n = cidx >> 3, gg = cidx & 7;
    *(bf16x8*)&Bs[n * 64 + (((gg ^ ((n >> 3) & 7))) << 3)] =
        *(const bf16x8*)(wb + (size_t)n * 64 + gg * 8);
  }

  const bool wr_h = (hout != nullptr) && (blockIdx.y == 0);
  const int gstride = gridDim.x;

  float4 a0, a1, rv0, rv1;
  auto loadA = [&](int tl, float4& x0, float4& x1, float4& r0v, float4& r1v) {
    x0 = make_float4(0.f, 0.f, 0.f, 0.f);
    x1 = make_float4(0.f, 0.f, 0.f, 0.f);
    r0v = make_float4(0.f, 0.f, 0.f, 0.f);
    r1v = make_float4(0.f, 0.f, 0.f, 0.f);
    int gr = tl * 32 + arow;
    if (tl < ntiles && gr < N) {
      x0 = *(const float4*)(src + (size_t)gr * 64 + ac0);
      x1 = *(const float4*)(src + (size_t)gr * 64 + ac0 + 4);
      if (resid) {
        r0v = *(const float4*)(resid + (size_t)gr * 64 + ac0);
        r1v = *(const float4*)(resid + (size_t)gr * 64 + ac0 + 4);
      }
    }
  };
  loadA(blockIdx.x, a0, a1, rv0, rv1);

  for (int tile = blockIdx.x; tile < ntiles; tile += gstride) {
    int r0 = tile * 32;
    int gr = r0 + arow;
    {
      float vs[8] = {a0.x, a0.y, a0.z, a0.w, a1.x, a1.y, a1.z, a1.w};
      if (bnsums) {
        float rv[8] = {rv0.x, rv0.y, rv0.z, rv0.w, rv1.x, rv1.y, rv1.z, rv1.w};
#pragma unroll
        for (int i = 0; i < 8; ++i) {
          float v = fmaf(vs[i], scale[i], shift[i]);
          float ge = 0.5f * v * (1.f + erff(v * 0.70710678118654752f));
          vs[i] = ge + rv[i];
        }
        if (wr_h && gr < N) {
          float4 o0 = {vs[0], vs[1], vs[2], vs[3]};
          float4 o1 = {vs[4], vs[5], vs[6], vs[7]};
          *(float4*)(hout + (size_t)gr * 64 + ac0) = o0;
          *(float4*)(hout + (size_t)gr * 64 + ac0 + 4) = o1;
        }
      }
      bf16x8 hi8;
#pragma unroll
      for (int i = 0; i < 8; ++i) hi8[i] = (short)f2bf(vs[i]);
      *(bf16x8*)&Ah[aoff] = hi8;
    }
    __syncthreads();

    // software pipeline: issue next tile's A loads under MFMA + epilogue
    loadA(tile + gstride, a0, a1, rv0, rv1);

    f32x4 acc[8];
#pragma unroll
    for (int s = 0; s < 8; ++s) acc[s] = (f32x4){0.f, 0.f, 0.f, 0.f};
    const int xq = m15 & 7;
#pragma unroll
    for (int kk = 0; kk < 64; kk += 32) {
      const int ga = (((kk >> 3) + quad) ^ xq) << 3;
      bf16x8 ah = *(const bf16x8*)&Ah[(rw + m15) * 64 + ga];
#pragma unroll
      for (int s = 0; s < 8; ++s) {
        // B row cw + m15*8 + s -> acc[s] holds output column cw + m15*8 + s
        bf16x8 b = *(const bf16x8*)&Bs[(cw + m15 * 8 + s) * 64 + ga];
        acc[s] = __builtin_amdgcn_mfma_f32_16x16x32_bf16(ah, b, acc[s], 0, 0, 0);
      }
    }
#pragma unroll
    for (int r = 0; r < 4; ++r) {
      int row_g = r0 + rw + quad * 4 + r;
      if (row_g < N) {
        int w0 = __builtin_amdgcn_cvt_pk_fp8_f32(acc[0][r], acc[1][r], 0, false);
        w0 = __builtin_amdgcn_cvt_pk_fp8_f32(acc[2][r], acc[3][r], w0, true);
        int w1 = __builtin_amdgcn_cvt_pk_fp8_f32(acc[4][r], acc[5][r], 0, false);
        w1 = __builtin_amdgcn_cvt_pk_fp8_f32(acc[6][r], acc[7][r], w1, true);
        uint2 o = {(unsigned)w0, (unsigned)w1};
        *(uint2*)(dst + (size_t)row_g * 256 + cw + m15 * 8) = o;
      }
    }
    __syncthreads();
  }
}

__global__ __launch_bounds__(256, 4) void k_mm0(const float* __restrict__ src,
                                                const unsigned short* __restrict__ wt,
                                                unsigned char* __restrict__ xlb,
                                                unsigned char* __restrict__ xrb,
                                                const int2* __restrict__ ebuf,
                                                const int* __restrict__ bktcnt,
                                                int* __restrict__ rowptr,
                                                int* __restrict__ colb,
                                                int* __restrict__ ccur,
                                                int N, int ntiles) {
  __shared__ __align__(16) char smem[36864];
  if (blockIdx.y == 2) {
    csr_pass2(ebuf, bktcnt, rowptr, colb, ccur, N, smem);
    return;
  }
  mm_gemm(src, nullptr, nullptr, nullptr, nullptr, nullptr, wt, xlb, xrb, N, ntiles, 0.f, smem);
}

__global__ __launch_bounds__(256, 4) void k_mm1(const float* __restrict__ src,
                                                const float* __restrict__ bnsums,
                                                const float* __restrict__ g,
                                                const float* __restrict__ be,
                                                float* __restrict__ hout,
                                                const unsigned short* __restrict__ wt,
                                                unsigned char* __restrict__ xlb,
                                                unsigned char* __restrict__ xrb,
                                                int N, int ntiles, float inv_n) {
  __shared__ __align__(16) char smem[36864];
  mm_gemm(src, bnsums, g, be, nullptr, hout, wt, xlb, xrb, N, ntiles, inv_n, smem);
}

__global__ __launch_bounds__(256, 4) void k_mm2(const float* __restrict__ src,
                                                const float* __restrict__ bnsums,
                                                const float* __restrict__ g,
                                                const float* __restrict__ be,
                                                const float* __restrict__ resid,
                                                float* __restrict__ hout,
                                                const unsigned short* __restrict__ wt,
                                                unsigned char* __restrict__ xlb,
                                                unsigned char* __restrict__ xrb,
                                                int N, int ntiles, float inv_n) {
  __shared__ __align__(16) char smem[36864];
  mm_gemm(src, bnsums, g, be, resid, hout, wt, xlb, xrb, N, ntiles, inv_n, smem);
}

// ---------------- GATv2: 2-edges-per-wave, fp8 gather rows, f32 math ----
// Lanes 0-31 carry edge A, lanes 32-63 edge B (8 fp8 channels/lane, dwordx2
// gather serves both edges; each edge row is 256B contiguous -> 4 cache lines
// per edge). Head = 8-lane group; score reduce = 3 DPP steps covering both
// edges at once.

static __device__ __forceinline__ void gat_body(const unsigned char* __restrict__ xlb,
                                                const unsigned char* __restrict__ xrb,
                                                const float* __restrict__ att,
                                                const float* __restrict__ bias,
                                                const int* __restrict__ rowptr,
                                                const int* __restrict__ colb,
                                                float* __restrict__ out,
                                                float* __restrict__ bnsums, int N) {
  __shared__ float sres[4][64];
  const int lane = threadIdx.x & 63;
  const int wv = threadIdx.x >> 6;
  const int half = lane >> 5; // which edge of the pair this lane serves
  const int l5 = lane & 31;
  const int node0 = blockIdx.x * 4 + wv;
  const bool valid = node0 < N;
  const int node = __builtin_amdgcn_readfirstlane(valid ? node0 : 0); // wave-uniform
  const int rp = rowptr[node];
  const int beg = rp & 0x3FFFFF;
  const int deg = (int)(((unsigned)rp) >> 22);
  const int end = valid ? beg + deg : beg;

  const unsigned char* xl = xlb; // wave-uniform base -> SADDR form
  const unsigned lb = (unsigned)l5 * 8u;

  auto sel = [&](int a, int b) { return (unsigned)(half ? b : a); };

  int4 c0 = *(const int4*)(colb + beg);     // edges 0..3 (16B-aligned: beg%4==0)
  int4 c1 = *(const int4*)(colb + beg + 4); // edges 4..7
  const unsigned self_off = (unsigned)(node << 8);
  uint2 vbs = *(const uint2*)(xl + self_off + lb);
  uint2 pd0 = *(const uint2*)(xl + (sel(c0.x, c0.y) + lb));
  uint2 pd1 = *(const uint2*)(xl + (sel(c0.z, c0.w) + lb));
  uint2 pt0 = *(const uint2*)(xl + (sel(c1.x, c1.y) + lb));
  uint2 pt1 = *(const uint2*)(xl + (sel(c1.z, c1.w) + lb));
  int4 cn = *(const int4*)(colb + beg + 8); // offsets for edges 8..11

  float4 aa = *(const float4*)(att + l5 * 8);
  float4 ab = *(const float4*)(att + l5 * 8 + 4);
  const float LOG2E = 1.4426950408889634f;
  const f32x2 a01 = {aa.x * LOG2E, aa.y * LOG2E};
  const f32x2 a23 = {aa.z * LOG2E, aa.w * LOG2E};
  const f32x2 a45 = {ab.x * LOG2E, ab.y * LOG2E};
  const f32x2 a67 = {ab.z * LOG2E, ab.w * LOG2E};
  const f32x2 c02 = {0.2f, 0.2f};
  uint2 xru = *(const uint2*)(xrb + self_off + lb);
  const f32x2 xr01 = __builtin_amdgcn_cvt_pk_f32_fp8((int)xru.x, false);
  const f32x2 xr23 = __builtin_amdgcn_cvt_pk_f32_fp8((int)xru.x, true);
  const f32x2 xr45 = __builtin_amdgcn_cvt_pk_f32_fp8((int)xru.y, false);
  const f32x2 xr67 = __builtin_amdgcn_cvt_pk_f32_fp8((int)xru.y, true);

  // score over 8 channels/lane, reduced across the 8-lane head group (both
  // halves reduce their own edge). Returns per-(head,edge) score; also yields
  // the converted channel values for the accumulation.
  auto score = [&](uint2 vb, f32x2& v01, f32x2& v23, f32x2& v45, f32x2& v67) -> float {
    v01 = __builtin_amdgcn_cvt_pk_f32_fp8((int)vb.x, false);
    v23 = __builtin_amdgcn_cvt_pk_f32_fp8((int)vb.x, true);
    v45 = __builtin_amdgcn_cvt_pk_f32_fp8((int)vb.y, false);
    v67 = __builtin_amdgcn_cvt_pk_f32_fp8((int)vb.y, true);
    f32x2 s01 = v01 + xr01;
    f32x2 s23 = v23 + xr23;
    f32x2 s45 = v45 + xr45;
    f32x2 s67 = v67 + xr67;
    s01 = __builtin_elementwise_max(s01, s01 * c02);
    s23 = __builtin_elementwise_max(s23, s23 * c02);
    s45 = __builtin_elementwise_max(s45, s45 * c02);
    s67 = __builtin_elementwise_max(s67, s67 * c02);
    f32x2 q = s01 * a01;
    q = __builtin_elementwise_fma(s23, a23, q);
    q = __builtin_elementwise_fma(s45, a45, q);
    q = __builtin_elementwise_fma(s67, a67, q);
    float p = q.x + q.y;
    p = DPP_ADD(p, 0xB1);  // quad_perm [1,0,3,2]
    p = DPP_ADD(p, 0x4E);  // quad_perm [2,3,0,1]
    p = DPP_ADD(p, 0x141); // row_half_mirror -> 8-lane (head) group sum
    return p;
  };

  f32x2 sv01, sv23, sv45, sv67;
  const float m = score(vbs, sv01, sv23, sv45, sv67); // self score (identical in both halves)

  const float hsel = half ? 0.f : 1.f; // self counted once (half 0)
  float lsum = hsel;
  const f32x2 hs2 = {hsel, hsel};
  f32x2 o01 = sv01 * hs2, o23 = sv23 * hs2, o45 = sv45 * hs2, o67 = sv67 * hs2;

  auto proc = [&](uint2 vb, int ebase) {
    f32x2 v01, v23, v45, v67;
    float p = score(vb, v01, v23, v45, v67);
    float w = __builtin_amdgcn_exp2f(fminf(p - m, 126.f));
    w = (ebase + half < end) ? w : 0.f;
    lsum += w;
    f32x2 w2 = {w, w};
    o01 = __builtin_elementwise_fma(w2, v01, o01);
    o23 = __builtin_elementwise_fma(w2, v23, o23);
    o45 = __builtin_elementwise_fma(w2, v45, o45);
    o67 = __builtin_elementwise_fma(w2, v67, o67);
  };

  for (int e = beg; e < end; e += 4) {
    uint2 pu0 = *(const uint2*)(xl + (sel(cn.x, cn.y) + lb));
    uint2 pu1 = *(const uint2*)(xl + (sel(cn.z, cn.w) + lb));
    cn = *(const int4*)(colb + e + 12);
    proc(pd0, e);
    proc(pd1, e + 2);
    pd0 = pt0; pd1 = pt1;
    pt0 = pu0; pt1 = pu1;
  }

  // per-(head) denominator: sum across the two edge-halves, then normalize
  lsum += __shfl_xor(lsum, 32, 64);
  float inv = __builtin_amdgcn_rcpf(lsum);
  float r[8] = {o01.x * inv, o01.y * inv, o23.x * inv, o23.y * inv,
                o45.x * inv, o45.y * inv, o67.x * inv, o67.y * inv};
#pragma unroll
  for (int j = 0; j < 8; ++j) {
    r[j] += __shfl_xor(r[j], 8, 64);  // head pairs
    r[j] += __shfl_xor(r[j], 16, 64); // all 4 heads
    r[j] += __shfl_xor(r[j], 32, 64); // edge halves
  }
  if (lane < 8) {
    float4 res0 = {0.f, 0.f, 0.f, 0.f}, res1 = {0.f, 0.f, 0.f, 0.f};
    if (valid) {
      float4 b0 = *(const float4*)(bias + lane * 8);
      float4 b1 = *(const float4*)(bias + lane * 8 + 4);
      res0.x = 0.25f * r[0] + b0.x;
      res0.y = 0.25f * r[1] + b0.y;
      res0.z = 0.25f * r[2] + b0.z;
      res0.w = 0.25f * r[3] + b0.w;
      res1.x = 0.25f * r[4] + b1.x;
      res1.y = 0.25f * r[5] + b1.y;
      res1.z = 0.25f * r[6] + b1.z;
      res1.w = 0.25f * r[7] + b1.w;
      *(float4*)(out + (size_t)node * 64 + lane * 8) = res0;
      *(float4*)(out + (size_t)node * 64 + lane * 8 + 4) = res1;
    }
    *(float4*)&sres[wv][lane * 8] = res0;
    *(float4*)&sres[wv][lane * 8 + 4] = res1;
  }
  __syncthreads();
  if (threadIdx.x < 64) {
    int c = threadIdx.x;
    float s0 = sres[0][c], s1 = sres[1][c], s2 = sres[2][c], s3 = sres[3][c];
    float* bs = bnsums + (size_t)(blockIdx.x & (NSHARD - 1)) * 128;
    atomicAdd(&bs[c], s0 + s1 + s2 + s3);
    atomicAdd(&bs[64 + c], s0 * s0 + s1 * s1 + s2 * s2 + s3 * s3);
  }
}

__global__ __launch_bounds__(256) void k_gat0(const unsigned char* __restrict__ xlb,
                                              const unsigned char* __restrict__ xrb,
                                              const float* __restrict__ att,
                                              const float* __restrict__ bias,
                                              const int* __restrict__ rowptr,
                                              const int* __restrict__ colb,
                                              float* __restrict__ out,
                                              float* __restrict__ bnsums, int N) {
  gat_body(xlb, xrb, att, bias, rowptr, colb, out, bnsums, N);
}
__global__ __launch_bounds__(256) void k_gat1(const unsigned char* __restrict__ xlb,
                                              const unsigned char* __restrict__ xrb,
                                              const float* __restrict__ att,
                                              const float* __restrict__ bias,
                                              const int* __restrict__ rowptr,
                                              const int* __restrict__ colb,
                                              float* __restrict__ out,
                                              float* __restrict__ bnsums, int N) {
  gat_body(xlb, xrb, att, bias, rowptr, colb, out, bnsums, N);
}
__global__ __launch_bounds__(256) void k_gat2(const unsigned char* __restrict__ xlb,
                                              const unsigned char* __restrict__ xrb,
                                              const float* __restrict__ att,
                                              const float* __restrict__ bias,
                                              const int* __restrict__ rowptr,
                                              const int* __restrict__ colb,
                                              float* __restrict__ out,
                                              float* __restrict__ bnsums, int N) {
  gat_body(xlb, xrb, att, bias, rowptr, colb, out, bnsums, N);
}

// ---------------- final: collapse shards -> BN+GELU+residual -> run-batched pool ----------------

__global__ __launch_bounds__(256) void k_bn_pool(const float* __restrict__ gat,
                                                 const float* __restrict__ bnsums,
                                                 const float* __restrict__ g,
                                                 const float* __restrict__ be,
                                                 const float* __restrict__ resid,
                                                 const int* __restrict__ batch,
                                                 float* __restrict__ pool,
                                                 int N, float inv_n) {
  __shared__ float sc[64], sh[64];
  if (threadIdx.x < 64) {
    int c = threadIdx.x;
    float s = 0.f, q = 0.f;
    for (int sd = 0; sd < NSHARD; ++sd) {
      s += bnsums[sd * 128 + c];
      q += bnsums[sd * 128 + 64 + c];
    }
    float mu = s * inv_n;
    float var = q * inv_n - mu * mu;
    float rs = rsqrtf(var + 1e-5f) * g[c];
    sc[c] = rs;
    sh[c] = be[c] - mu * rs;
  }
  __syncthreads();
  const int c = threadIdx.x & 63;
  const int wv = threadIdx.x >> 6;
  int n0 = (blockIdx.x * 4 + wv) * 32;
  if (n0 >= N) return;
  int n1 = min(n0 + 32, N);
  int curg = batch[n0]; // wave-uniform (batch sorted)
  float acc = 0.f;
  for (int n = n0; n < n1; ++n) {
    int b = batch[n];
    if (b != curg) {
      atomicAdd(&pool[(size_t)curg * 64 + c], acc);
      acc = 0.f;
      curg = b;
    }
    float v = fmaf(gat[(size_t)n * 64 + c], sc[c], sh[c]);
    float ge = 0.5f * v * (1.f + erff(v * 0.70710678118654752f));
    acc += ge + resid[(size_t)n * 64 + c];
  }
  atomicAdd(&pool[(size_t)curg * 64 + c], acc);
}

// ---------------- heads ----------------

__global__ void k_head(const float* __restrict__ pool, const float* __restrict__ Wmu,
                       const float* __restrict__ bmu, const float* __restrict__ Wlv,
                       const float* __restrict__ blv, float* __restrict__ out, int G) {
  int g = blockIdx.x;
  int c = threadIdx.x; // 64 threads
  __shared__ float row[64];
  row[c] = pool[(size_t)g * 64 + c];
  __syncthreads();
  float am = 0.f, al = 0.f;
  for (int k = 0; k < 64; ++k) {
    float r = row[k];
    am = fmaf(r, Wmu[k * 64 + c], am);
    al = fmaf(r, Wlv[k * 64 + c], al);
  }
  out[(size_t)g * 64 + c] = am + bmu[c];
  out[(size_t)G * 64 + (size_t)g * 64 + c] = al + blv[c];
}

// ---------------- launch ----------------

extern "C" void kernel_launch(void* const* d_in, const int* in_sizes, int n_in,
                              void* d_out, int out_size, void* d_ws, size_t ws_size,
                              hipStream_t stream) {
  const float* x    = (const float*)d_in[0];
  const int* esrc   = (const int*)d_in[1];
  const int* edst   = (const int*)d_in[2];
  const int* batch  = (const int*)d_in[3];
  const float* Wl[3]  = {(const float*)d_in[5],  (const float*)d_in[11], (const float*)d_in[17]};
  const float* Wr[3]  = {(const float*)d_in[6],  (const float*)d_in[12], (const float*)d_in[18]};
  const float* att[3] = {(const float*)d_in[7],  (const float*)d_in[13], (const float*)d_in[19]};
  const float* bia[3] = {(const float*)d_in[8],  (const float*)d_in[14], (const float*)d_in[20]};
  const float* gam[3] = {(const float*)d_in[9],  (const float*)d_in[15], (const float*)d_in[21]};
  const float* bet[3] = {(const float*)d_in[10], (const float*)d_in[16], (const float*)d_in[22]};
  const float* Wmu = (const float*)d_in[23];
  const float* bmu = (const float*)d_in[24];
  const float* Wlv = (const float*)d_in[25];
  const float* blv = (const float*)d_in[26];
  float* out = (float*)d_out;

  const int N = in_sizes[0] / 64;
  const int E = in_sizes[1];
  const int G = out_size / 128;
  const int nbk = (N + 255) / 256;

  char* p = (char*)d_ws;
  auto alloc = [&](size_t bytes) -> void* {
    void* r = (void*)p;
    p += (bytes + 255) & ~(size_t)255;
    return r;
  };
  // zero-init region first (one memset: bktcnt + bnsums + pool + ccur + colb)
  int*   bktcnt  = (int*)alloc(256 * 4);
  float* bnsums  = (float*)alloc(3 * NSHARD * 128 * 4);
  float* pool    = (float*)alloc((size_t)G * 64 * 4);
  int*   ccur    = (int*)alloc(256);
  int*   colb    = (int*)alloc(((size_t)E + 3 * (size_t)N + 64) * 4); // 4-padded rows + zero tail
  char*  zend    = p;
  unsigned char* xlb = (unsigned char*)alloc((size_t)N * 256);
  unsigned char* xrb = (unsigned char*)alloc((size_t)N * 256);
  float* hA     = (float*)alloc((size_t)N * 64 * 4);
  float* hB     = (float*)alloc((size_t)N * 64 * 4);
  float* gat    = (float*)alloc((size_t)N * 64 * 4);
  int*   rowptr = (int*)alloc((size_t)(N + 1) * 4);
  int2*  ebuf   = (int2*)alloc((size_t)nbk * ECAP * 8);
  unsigned short* wt = (unsigned short*)alloc(6 * 16384 * 2);

  const int nbGat = (N + 3) / 4;
  const int ntiles = (N + 31) / 32;
  const float inv_n = 1.f / (float)N;

  hipMemsetAsync(bktcnt, 0, (size_t)(zend - (char*)bktcnt), stream);

  // ---- CSR build: W-prep + single-pass bucket place (fused) ----
  k_prep<<<384 + NEB, 256, 0, stream>>>(Wl[0], Wr[0], Wl[1], Wr[1], Wl[2], Wr[2], wt,
                                        esrc, edst, bktcnt, ebuf, E, N);

  float* bns0 = bnsums;
  float* bns1 = bnsums + NSHARD * 128;
  float* bns2 = bnsums + 2 * NSHARD * 128;

  // ---- layer 0 (y=2 partition finalizes CSR concurrently with the GEMM) ----
  k_mm0<<<dim3(512, 3), 256, 0, stream>>>(x, wt, xlb, xrb, ebuf, bktcnt, rowptr, colb,
                                          ccur, N, ntiles);
  k_gat0<<<nbGat, 256, 0, stream>>>(xlb, xrb, att[0], bia[0], rowptr, colb, gat, bns0, N);
  // ---- layer 1 (applies h0 = gelu(bn0(gat0))) ----
  k_mm1<<<dim3(512, 2), 256, 0, stream>>>(gat, bns0, gam[0], bet[0], hA,
                                          wt + 2 * 16384, xlb, xrb, N, ntiles, inv_n);
  k_gat1<<<nbGat, 256, 0, stream>>>(xlb, xrb, att[1], bia[1], rowptr, colb, gat, bns1, N);
  // ---- layer 2 (applies h1 = gelu(bn1(gat1)) + h0) ----
  k_mm2<<<dim3(512, 2), 256, 0, stream>>>(gat, bns1, gam[1], bet[1], hA, hB,
                                          wt + 4 * 16384, xlb, xrb, N, ntiles, inv_n);
  k_gat2<<<nbGat, 256, 0, stream>>>(xlb, xrb, att[2], bia[2], rowptr, colb, gat, bns2, N);
  // ---- final: h2 = gelu(bn2(gat2)) + h1 -> pool ----
  k_bn_pool<<<(N + 127) / 128, 256, 0, stream>>>(gat, bns2, gam[2], bet[2], hB, batch, pool,
                                                 N, inv_n);
  k_head<<<G, 64, 0, stream>>>(pool, Wmu, bmu, Wlv, blv, out, G);
}

// Round 13
// 368.286 us; speedup vs baseline: 1.1863x; 1.0072x over previous
//
#include <hip/hip_runtime.h>
#include <math.h>

typedef __attribute__((ext_vector_type(8))) short bf16x8;
typedef __attribute__((ext_vector_type(4))) float f32x4;
typedef __attribute__((ext_vector_type(2))) float f32x2;

static __device__ __forceinline__ unsigned short f2bf(float f) {
  unsigned u = __float_as_uint(f);
  unsigned r = (u + 0x7FFF + ((u >> 16) & 1)) >> 16; // RNE
  return (unsigned short)r;
}

// DPP add: x += lane-permuted x. bound_ctrl=true + bijective ctrl (quad_perm /
// row_half_mirror) lets GCNDPPCombine fold the mov_dpp into v_add_f32_dpp.
// (round-10 form — measured best; old=src/bound_ctrl=false regressed 10%)
#define DPP_ADD(x, ctrl) \
  ((x) + __int_as_float(__builtin_amdgcn_update_dpp(0, __float_as_int(x), (ctrl), 0xf, 0xf, true)))

#define NSHARD 64
#define NEB 256   // edge-chunk blocks for the place pass
#define ECAP 6144 // fixed bucket stride in ebuf (mean fill 4096, sigma 64)

// ---------------- W-prep + single-pass bucket place ----------------

__global__ __launch_bounds__(256) void k_prep(const float* __restrict__ W0, const float* __restrict__ W1,
                                              const float* __restrict__ W2, const float* __restrict__ W3,
                                              const float* __restrict__ W4, const float* __restrict__ W5,
                                              unsigned short* __restrict__ wt,
                                              const int* __restrict__ esrc,
                                              const int* __restrict__ edst,
                                              int* __restrict__ bktcnt,
                                              int2* __restrict__ ebuf, int E, int N) {
  if (blockIdx.x < 384) {
    int gid = blockIdx.x * 256 + threadIdx.x; // 6 * 16384
    int m = gid >> 14;
    int r = gid & 16383;
    int k = r >> 8;
    int n = r & 255;
    const float* W = (m == 0) ? W0 : (m == 1) ? W1 : (m == 2) ? W2
                   : (m == 3) ? W3 : (m == 4) ? W4 : W5;
    wt[(size_t)m * 16384 + n * 64 + k] = f2bf(W[k * 256 + n]);
    return;
  }
  const int b = blockIdx.x - 384;
  const int nbk = (N + 255) >> 8;
  __shared__ int cnt[256], base[256];
  cnt[threadIdx.x] = 0;
  __syncthreads();
  const int chunk = (E + NEB - 1) / NEB;
  const int e0 = b * chunk, e1 = min(e0 + chunk, E);
  for (int e = e0 + threadIdx.x; e < e1; e += 256) atomicAdd(&cnt[edst[e] >> 8], 1);
  __syncthreads();
  if (threadIdx.x < nbk && cnt[threadIdx.x])
    base[threadIdx.x] = atomicAdd(&bktcnt[threadIdx.x], cnt[threadIdx.x]);
  cnt[threadIdx.x] = 0; // reuse as local cursor (own-index only before sync)
  __syncthreads();
  for (int e = e0 + threadIdx.x; e < e1; e += 256) {
    int d = edst[e];
    int bk = d >> 8;
    int p = base[bk] + atomicAdd(&cnt[bk], 1);
    ebuf[(size_t)bk * ECAP + p] = make_int2(d, esrc[e]);
  }
}

// ---------------- pass2 (y=2 of k_mm0): per-bucket CSR finalize, 4-padded ----------------
// Per-node lists padded to %4 (pad slots stay 0 from memset -> safe gather of row 0,
// masked by deg). rowptr packs pos|deg<<22. colb space reserved via global cursor.

static __device__ __forceinline__ void csr_pass2(const int2* __restrict__ ebuf,
                                                 const int* __restrict__ bktcnt,
                                                 int* __restrict__ rowptr,
                                                 int* __restrict__ colb,
                                                 int* __restrict__ ccur,
                                                 int N, char* smem) {
  const int b = blockIdx.x;
  const int nbk = (N + 255) >> 8;
  if (b >= nbk) return;
  int* hist = (int*)smem;          // 256
  int* s = (int*)smem + 256;       // 256 (scan buffer)
  int* sb = (int*)smem + 512;      // 1 (bucket colb-base broadcast)
  const int tid = threadIdx.x;
  const int lo = b * ECAP;
  const int hi = lo + bktcnt[b];
  hist[tid] = 0;
  __syncthreads();
  for (int i = lo + tid; i < hi; i += 256) atomicAdd(&hist[ebuf[i].x & 255], 1);
  __syncthreads();
  int deg = hist[tid];
  int pd = (deg + 3) & ~3;
  s[tid] = pd;
  __syncthreads();
  for (int off = 1; off < 256; off <<= 1) {
    int t = (tid >= off) ? s[tid - off] : 0;
    __syncthreads();
    s[tid] += t;
    __syncthreads();
  }
  if (tid == 255) sb[0] = atomicAdd(ccur, s[255]);
  __syncthreads();
  int pos = sb[0] + s[tid] - pd; // exclusive prefix of padded degrees
  int node = (b << 8) + tid;
  if (node < N) rowptr[node] = (int)((unsigned)pos | ((unsigned)deg << 22));
  hist[tid] = pos; // reuse as global cursor
  __syncthreads();
  for (int i = lo + tid; i < hi; i += 256) {
    int2 e = ebuf[i];
    int p = atomicAdd(&hist[e.x & 255], 1);
    colb[p] = e.y << 8; // byte offset into fp8 rows (256 fp8 = 256 B)
  }
}

// ---------------- MFMA dual GEMM + fused BN/GELU/residual producer (shared body) ----
// Gather copies (xlb/xrb) stored as OCP fp8 e4m3 (256 B/row) — consumed only by
// k_gat. Single-bf16 GEMM (outputs fp8-quantized anyway; hout keeps f32 quality).

static __device__ __forceinline__ void mm_gemm(const float* __restrict__ src,
                                               const float* __restrict__ bnsums,
                                               const float* __restrict__ g,
                                               const float* __restrict__ be,
                                               const float* __restrict__ resid,
                                               float* __restrict__ hout,
                                               const unsigned short* __restrict__ wt,
                                               unsigned char* __restrict__ xlb,
                                               unsigned char* __restrict__ xrb,
                                               int N, int ntiles, float inv_n,
                                               char* smem) {
  unsigned short* Bs = (unsigned short*)smem;           // 256*64 shorts, swizzled
  unsigned short* Ah = (unsigned short*)(smem + 32768); // 32*64
  const int t = threadIdx.x;
  const unsigned short* wb = wt + (blockIdx.y ? 16384 : 0);
  unsigned char* dst = blockIdx.y ? xrb : xlb;

  const int wave = t >> 6, lane = t & 63;
  const int rw = (wave & 1) * 16, cw = (wave >> 1) * 128;
  const int m15 = lane & 15, quad = lane >> 4;
  const int arow = t >> 3, ac0 = (t & 7) * 8;
  const int aoff = arow * 64 + (((t & 7) ^ (arow & 7)) << 3); // swizzled A slot

  float scale[8], shift[8];
  if (bnsums) {
    float* stat = (float*)smem; // overlay: consumed before Bs fill
    if (t < 128) {
      float a = 0.f;
#pragma unroll
      for (int sd = 0; sd < NSHARD; ++sd) a += bnsums[sd * 128 + t];
      stat[t] = a;
    }
    __syncthreads();
#pragma unroll
    for (int i = 0; i < 8; ++i) {
      int c = ac0 + i;
      float mu = stat[c] * inv_n;
      float var = stat[64 + c] * inv_n - mu * mu;
      float rs = rsqrtf(var + 1e-5f) * g[c];
      scale[i] = rs;
      shift[i] = be[c] - mu * rs;
    }
    __syncthreads(); // stat reads done before Bs fill overwrites
  }

#pragma unroll
  for (int j = 0; j < 8; ++j) {
    int cidx = t + 256 * j;
    int n = cidx >> 3, gg = cidx & 7;
    *(bf16x8*)&Bs[n * 64 + (((gg ^ ((n >> 3) & 7))) << 3)] =
        *(const bf16x8*)(wb + (size_t)n * 64 + gg * 8);
  }

  const bool wr_h = (hout != nullptr) && (blockIdx.y == 0);
  const int gstride = gridDim.x;

  float4 a0, a1, rv0, rv1;
  auto loadA = [&](int tl, float4& x0, float4& x1, float4& r0v, float4& r1v) {
    x0 = make_float4(0.f, 0.f, 0.f, 0.f);
    x1 = make_float4(0.f, 0.f, 0.f, 0.f);
    r0v = make_float4(0.f, 0.f, 0.f, 0.f);
    r1v = make_float4(0.f, 0.f, 0.f, 0.f);
    int gr = tl * 32 + arow;
    if (tl < ntiles && gr < N) {
      x0 = *(const float4*)(src + (size_t)gr * 64 + ac0);
      x1 = *(const float4*)(src + (size_t)gr * 64 + ac0 + 4);
      if (resid) {
        r0v = *(const float4*)(resid + (size_t)gr * 64 + ac0);
        r1v = *(const float4*)(resid + (size_t)gr * 64 + ac0 + 4);
      }
    }
  };
  loadA(blockIdx.x, a0, a1, rv0, rv1);

  for (int tile = blockIdx.x; tile < ntiles; tile += gstride) {
    int r0 = tile * 32;
    int gr = r0 + arow;
    {
      float vs[8] = {a0.x, a0.y, a0.z, a0.w, a1.x, a1.y, a1.z, a1.w};
      if (bnsums) {
        float rv[8] = {rv0.x, rv0.y, rv0.z, rv0.w, rv1.x, rv1.y, rv1.z, rv1.w};
#pragma unroll
        for (int i = 0; i < 8; ++i) {
          float v = fmaf(vs[i], scale[i], shift[i]);
          float ge = 0.5f * v * (1.f + erff(v * 0.70710678118654752f));
          vs[i] = ge + rv[i];
        }
        if (wr_h && gr < N) {
          float4 o0 = {vs[0], vs[1], vs[2], vs[3]};
          float4 o1 = {vs[4], vs[5], vs[6], vs[7]};
          *(float4*)(hout + (size_t)gr * 64 + ac0) = o0;
          *(float4*)(hout + (size_t)gr * 64 + ac0 + 4) = o1;
        }
      }
      bf16x8 hi8;
#pragma unroll
      for (int i = 0; i < 8; ++i) hi8[i] = (short)f2bf(vs[i]);
      *(bf16x8*)&Ah[aoff] = hi8;
    }
    __syncthreads();

    // software pipeline: issue next tile's A loads under MFMA + epilogue
    loadA(tile + gstride, a0, a1, rv0, rv1);

    f32x4 acc[8];
#pragma unroll
    for (int s = 0; s < 8; ++s) acc[s] = (f32x4){0.f, 0.f, 0.f, 0.f};
    const int xq = m15 & 7;
#pragma unroll
    for (int kk = 0; kk < 64; kk += 32) {
      const int ga = (((kk >> 3) + quad) ^ xq) << 3;
      bf16x8 ah = *(const bf16x8*)&Ah[(rw + m15) * 64 + ga];
#pragma unroll
      for (int s = 0; s < 8; ++s) {
        // B row cw + m15*8 + s -> acc[s] holds output column cw + m15*8 + s
        bf16x8 b = *(const bf16x8*)&Bs[(cw + m15 * 8 + s) * 64 + ga];
        acc[s] = __builtin_amdgcn_mfma_f32_16x16x32_bf16(ah, b, acc[s], 0, 0, 0);
      }
    }
#pragma unroll
    for (int r = 0; r < 4; ++r) {
      int row_g = r0 + rw + quad * 4 + r;
      if (row_g < N) {
        int w0 = __builtin_amdgcn_cvt_pk_fp8_f32(acc[0][r], acc[1][r], 0, false);
        w0 = __builtin_amdgcn_cvt_pk_fp8_f32(acc[2][r], acc[3][r], w0, true);
        int w1 = __builtin_amdgcn_cvt_pk_fp8_f32(acc[4][r], acc[5][r], 0, false);
        w1 = __builtin_amdgcn_cvt_pk_fp8_f32(acc[6][r], acc[7][r], w1, true);
        uint2 o = {(unsigned)w0, (unsigned)w1};
        *(uint2*)(dst + (size_t)row_g * 256 + cw + m15 * 8) = o;
      }
    }
    __syncthreads();
  }
}

__global__ __launch_bounds__(256, 4) void k_mm0(const float* __restrict__ src,
                                                const unsigned short* __restrict__ wt,
                                                unsigned char* __restrict__ xlb,
                                                unsigned char* __restrict__ xrb,
                                                const int2* __restrict__ ebuf,
                                                const int* __restrict__ bktcnt,
                                                int* __restrict__ rowptr,
                                                int* __restrict__ colb,
                                                int* __restrict__ ccur,
                                                int N, int ntiles) {
  __shared__ __align__(16) char smem[36864];
  if (blockIdx.y == 2) {
    csr_pass2(ebuf, bktcnt, rowptr, colb, ccur, N, smem);
    return;
  }
  mm_gemm(src, nullptr, nullptr, nullptr, nullptr, nullptr, wt, xlb, xrb, N, ntiles, 0.f, smem);
}

__global__ __launch_bounds__(256, 4) void k_mm1(const float* __restrict__ src,
                                                const float* __restrict__ bnsums,
                                                const float* __restrict__ g,
                                                const float* __restrict__ be,
                                                float* __restrict__ hout,
                                                const unsigned short* __restrict__ wt,
                                                unsigned char* __restrict__ xlb,
                                                unsigned char* __restrict__ xrb,
                                                int N, int ntiles, float inv_n) {
  __shared__ __align__(16) char smem[36864];
  mm_gemm(src, bnsums, g, be, nullptr, hout, wt, xlb, xrb, N, ntiles, inv_n, smem);
}

__global__ __launch_bounds__(256, 4) void k_mm2(const float* __restrict__ src,
                                                const float* __restrict__ bnsums,
                                                const float* __restrict__ g,
                                                const float* __restrict__ be,
                                                const float* __restrict__ resid,
                                                float* __restrict__ hout,
                                                const unsigned short* __restrict__ wt,
                                                unsigned char* __restrict__ xlb,
                                                unsigned char* __restrict__ xrb,
                                                int N, int ntiles, float inv_n) {
  __shared__ __align__(16) char smem[36864];
  mm_gemm(src, bnsums, g, be, resid, hout, wt, xlb, xrb, N, ntiles, inv_n, smem);
}

// ---------------- GATv2: 2-edges-per-wave, fp8 gather rows, 3-stage prefetch ----
// Lanes 0-31 carry edge A, lanes 32-63 edge B (8 fp8 channels/lane, dwordx2
// gather serves both edges). Head = 8-lane group; score reduce = 3 DPP steps.
// Gather pipeline deepened to 3 stages (12 edges resident, ~4 loads in flight
// per wave) — round-11's occupancy experiment showed time ∝ 1/waves-in-flight,
// i.e. gather-latency-bound; more MLP per wave attacks that directly.

static __device__ __forceinline__ void gat_body(const unsigned char* __restrict__ xlb,
                                                const unsigned char* __restrict__ xrb,
                                                const float* __restrict__ att,
                                                const float* __restrict__ bias,
                                                const int* __restrict__ rowptr,
                                                const int* __restrict__ colb,
                                                float* __restrict__ out,
                                                float* __restrict__ bnsums, int N) {
  __shared__ float sres[4][64];
  const int lane = threadIdx.x & 63;
  const int wv = threadIdx.x >> 6;
  const int half = lane >> 5; // which edge of the pair this lane serves
  const int l5 = lane & 31;
  const int node0 = blockIdx.x * 4 + wv;
  const bool valid = node0 < N;
  const int node = __builtin_amdgcn_readfirstlane(valid ? node0 : 0); // wave-uniform
  const int rp = rowptr[node];
  const int beg = rp & 0x3FFFFF;
  const int deg = (int)(((unsigned)rp) >> 22);
  const int end = valid ? beg + deg : beg;

  const unsigned char* xl = xlb; // wave-uniform base -> SADDR form
  const unsigned lb = (unsigned)l5 * 8u;

  auto sel = [&](int a, int b) { return (unsigned)(half ? b : a); };

  int4 c0 = *(const int4*)(colb + beg);      // edges 0..3 (16B-aligned: beg%4==0)
  int4 c1 = *(const int4*)(colb + beg + 4);  // edges 4..7
  int4 c2 = *(const int4*)(colb + beg + 8);  // edges 8..11
  const unsigned self_off = (unsigned)(node << 8);
  uint2 vbs = *(const uint2*)(xl + self_off + lb);
  uint2 pd0 = *(const uint2*)(xl + (sel(c0.x, c0.y) + lb));
  uint2 pd1 = *(const uint2*)(xl + (sel(c0.z, c0.w) + lb));
  uint2 pt0 = *(const uint2*)(xl + (sel(c1.x, c1.y) + lb));
  uint2 pt1 = *(const uint2*)(xl + (sel(c1.z, c1.w) + lb));
  uint2 pu0 = *(const uint2*)(xl + (sel(c2.x, c2.y) + lb));
  uint2 pu1 = *(const uint2*)(xl + (sel(c2.z, c2.w) + lb));
  int4 cn = *(const int4*)(colb + beg + 12); // offsets for edges 12..15

  float4 aa = *(const float4*)(att + l5 * 8);
  float4 ab = *(const float4*)(att + l5 * 8 + 4);
  const float LOG2E = 1.4426950408889634f;
  const f32x2 a01 = {aa.x * LOG2E, aa.y * LOG2E};
  const f32x2 a23 = {aa.z * LOG2E, aa.w * LOG2E};
  const f32x2 a45 = {ab.x * LOG2E, ab.y * LOG2E};
  const f32x2 a67 = {ab.z * LOG2E, ab.w * LOG2E};
  const f32x2 c02 = {0.2f, 0.2f};
  uint2 xru = *(const uint2*)(xrb + self_off + lb);
  const f32x2 xr01 = __builtin_amdgcn_cvt_pk_f32_fp8((int)xru.x, false);
  const f32x2 xr23 = __builtin_amdgcn_cvt_pk_f32_fp8((int)xru.x, true);
  const f32x2 xr45 = __builtin_amdgcn_cvt_pk_f32_fp8((int)xru.y, false);
  const f32x2 xr67 = __builtin_amdgcn_cvt_pk_f32_fp8((int)xru.y, true);

  // score over 8 channels/lane, reduced across the 8-lane head group (both
  // halves reduce their own edge). Returns per-(head,edge) score; also yields
  // the converted channel values for the accumulation.
  auto score = [&](uint2 vb, f32x2& v01, f32x2& v23, f32x2& v45, f32x2& v67) -> float {
    v01 = __builtin_amdgcn_cvt_pk_f32_fp8((int)vb.x, false);
    v23 = __builtin_amdgcn_cvt_pk_f32_fp8((int)vb.x, true);
    v45 = __builtin_amdgcn_cvt_pk_f32_fp8((int)vb.y, false);
    v67 = __builtin_amdgcn_cvt_pk_f32_fp8((int)vb.y, true);
    f32x2 s01 = v01 + xr01;
    f32x2 s23 = v23 + xr23;
    f32x2 s45 = v45 + xr45;
    f32x2 s67 = v67 + xr67;
    s01 = __builtin_elementwise_max(s01, s01 * c02);
    s23 = __builtin_elementwise_max(s23, s23 * c02);
    s45 = __builtin_elementwise_max(s45, s45 * c02);
    s67 = __builtin_elementwise_max(s67, s67 * c02);
    f32x2 q = s01 * a01;
    q = __builtin_elementwise_fma(s23, a23, q);
    q = __builtin_elementwise_fma(s45, a45, q);
    q = __builtin_elementwise_fma(s67, a67, q);
    float p = q.x + q.y;
    p = DPP_ADD(p, 0xB1);  // quad_perm [1,0,3,2]
    p = DPP_ADD(p, 0x4E);  // quad_perm [2,3,0,1]
    p = DPP_ADD(p, 0x141); // row_half_mirror -> 8-lane (head) group sum
    return p;
  };

  f32x2 sv01, sv23, sv45, sv67;
  const float m = score(vbs, sv01, sv23, sv45, sv67); // self score (identical in both halves)

  const float hsel = half ? 0.f : 1.f; // self counted once (half 0)
  float lsum = hsel;
  const f32x2 hs2 = {hsel, hsel};
  f32x2 o01 = sv01 * hs2, o23 = sv23 * hs2, o45 = sv45 * hs2, o67 = sv67 * hs2;

  auto proc = [&](uint2 vb, int ebase) {
    f32x2 v01, v23, v45, v67;
    float p = score(vb, v01, v23, v45, v67);
    float w = __builtin_amdgcn_exp2f(fminf(p - m, 126.f));
    w = (ebase + half < end) ? w : 0.f;
    lsum += w;
    f32x2 w2 = {w, w};
    o01 = __builtin_elementwise_fma(w2, v01, o01);
    o23 = __builtin_elementwise_fma(w2, v23, o23);
    o45 = __builtin_elementwise_fma(w2, v45, o45);
    o67 = __builtin_elementwise_fma(w2, v67, o67);
  };

  for (int e = beg; e < end; e += 4) {
    uint2 pv0 = *(const uint2*)(xl + (sel(cn.x, cn.y) + lb));
    uint2 pv1 = *(const uint2*)(xl + (sel(cn.z, cn.w) + lb));
    cn = *(const int4*)(colb + e + 16);
    proc(pd0, e);
    proc(pd1, e + 2);
    pd0 = pt0; pd1 = pt1;
    pt0 = pu0; pt1 = pu1;
    pu0 = pv0; pu1 = pv1;
  }

  // per-(head) denominator: sum across the two edge-halves, then normalize
  lsum += __shfl_xor(lsum, 32, 64);
  float inv = __builtin_amdgcn_rcpf(lsum);
  float r[8] = {o01.x * inv, o01.y * inv, o23.x * inv, o23.y * inv,
                o45.x * inv, o45.y * inv, o67.x * inv, o67.y * inv};
#pragma unroll
  for (int j = 0; j < 8; ++j) {
    r[j] += __shfl_xor(r[j], 8, 64);  // head pairs
    r[j] += __shfl_xor(r[j], 16, 64); // all 4 heads
    r[j] += __shfl_xor(r[j], 32, 64); // edge halves
  }
  if (lane < 8) {
    float4 res0 = {0.f, 0.f, 0.f, 0.f}, res1 = {0.f, 0.f, 0.f, 0.f};
    if (valid) {
      float4 b0 = *(const float4*)(bias + lane * 8);
      float4 b1 = *(const float4*)(bias + lane * 8 + 4);
      res0.x = 0.25f * r[0] + b0.x;
      res0.y = 0.25f * r[1] + b0.y;
      res0.z = 0.25f * r[2] + b0.z;
      res0.w = 0.25f * r[3] + b0.w;
      res1.x = 0.25f * r[4] + b1.x;
      res1.y = 0.25f * r[5] + b1.y;
      res1.z = 0.25f * r[6] + b1.z;
      res1.w = 0.25f * r[7] + b1.w;
      *(float4*)(out + (size_t)node * 64 + lane * 8) = res0;
      *(float4*)(out + (size_t)node * 64 + lane * 8 + 4) = res1;
    }
    *(float4*)&sres[wv][lane * 8] = res0;
    *(float4*)&sres[wv][lane * 8 + 4] = res1;
  }
  __syncthreads();
  if (threadIdx.x < 64) {
    int c = threadIdx.x;
    float s0 = sres[0][c], s1 = sres[1][c], s2 = sres[2][c], s3 = sres[3][c];
    float* bs = bnsums + (size_t)(blockIdx.x & (NSHARD - 1)) * 128;
    atomicAdd(&bs[c], s0 + s1 + s2 + s3);
    atomicAdd(&bs[64 + c], s0 * s0 + s1 * s1 + s2 * s2 + s3 * s3);
  }
}

__global__ __launch_bounds__(256) void k_gat0(const unsigned char* __restrict__ xlb,
                                              const unsigned char* __restrict__ xrb,
                                              const float* __restrict__ att,
                                              const float* __restrict__ bias,
                                              const int* __restrict__ rowptr,
                                              const int* __restrict__ colb,
                                              float* __restrict__ out,
                                              float* __restrict__ bnsums, int N) {
  gat_body(xlb, xrb, att, bias, rowptr, colb, out, bnsums, N);
}
__global__ __launch_bounds__(256) void k_gat1(const unsigned char* __restrict__ xlb,
                                              const unsigned char* __restrict__ xrb,
                                              const float* __restrict__ att,
                                              const float* __restrict__ bias,
                                              const int* __restrict__ rowptr,
                                              const int* __restrict__ colb,
                                              float* __restrict__ out,
                                              float* __restrict__ bnsums, int N) {
  gat_body(xlb, xrb, att, bias, rowptr, colb, out, bnsums, N);
}
__global__ __launch_bounds__(256) void k_gat2(const unsigned char* __restrict__ xlb,
                                              const unsigned char* __restrict__ xrb,
                                              const float* __restrict__ att,
                                              const float* __restrict__ bias,
                                              const int* __restrict__ rowptr,
                                              const int* __restrict__ colb,
                                              float* __restrict__ out,
                                              float* __restrict__ bnsums, int N) {
  gat_body(xlb, xrb, att, bias, rowptr, colb, out, bnsums, N);
}

// ---------------- final: collapse shards -> BN+GELU+residual -> run-batched pool ----------------

__global__ __launch_bounds__(256) void k_bn_pool(const float* __restrict__ gat,
                                                 const float* __restrict__ bnsums,
                                                 const float* __restrict__ g,
                                                 const float* __restrict__ be,
                                                 const float* __restrict__ resid,
                                                 const int* __restrict__ batch,
                                                 float* __restrict__ pool,
                                                 int N, float inv_n) {
  __shared__ float sc[64], sh[64];
  if (threadIdx.x < 64) {
    int c = threadIdx.x;
    float s = 0.f, q = 0.f;
    for (int sd = 0; sd < NSHARD; ++sd) {
      s += bnsums[sd * 128 + c];
      q += bnsums[sd * 128 + 64 + c];
    }
    float mu = s * inv_n;
    float var = q * inv_n - mu * mu;
    float rs = rsqrtf(var + 1e-5f) * g[c];
    sc[c] = rs;
    sh[c] = be[c] - mu * rs;
  }
  __syncthreads();
  const int c = threadIdx.x & 63;
  const int wv = threadIdx.x >> 6;
  int n0 = (blockIdx.x * 4 + wv) * 32;
  if (n0 >= N) return;
  int n1 = min(n0 + 32, N);
  int curg = batch[n0]; // wave-uniform (batch sorted)
  float acc = 0.f;
  for (int n = n0; n < n1; ++n) {
    int b = batch[n];
    if (b != curg) {
      atomicAdd(&pool[(size_t)curg * 64 + c], acc);
      acc = 0.f;
      curg = b;
    }
    float v = fmaf(gat[(size_t)n * 64 + c], sc[c], sh[c]);
    float ge = 0.5f * v * (1.f + erff(v * 0.70710678118654752f));
    acc += ge + resid[(size_t)n * 64 + c];
  }
  atomicAdd(&pool[(size_t)curg * 64 + c], acc);
}

// ---------------- heads ----------------

__global__ void k_head(const float* __restrict__ pool, const float* __restrict__ Wmu,
                       const float* __restrict__ bmu, const float* __restrict__ Wlv,
                       const float* __restrict__ blv, float* __restrict__ out, int G) {
  int g = blockIdx.x;
  int c = threadIdx.x; // 64 threads
  __shared__ float row[64];
  row[c] = pool[(size_t)g * 64 + c];
  __syncthreads();
  float am = 0.f, al = 0.f;
  for (int k = 0; k < 64; ++k) {
    float r = row[k];
    am = fmaf(r, Wmu[k * 64 + c], am);
    al = fmaf(r, Wlv[k * 64 + c], al);
  }
  out[(size_t)g * 64 + c] = am + bmu[c];
  out[(size_t)G * 64 + (size_t)g * 64 + c] = al + blv[c];
}

// ---------------- launch ----------------

extern "C" void kernel_launch(void* const* d_in, const int* in_sizes, int n_in,
                              void* d_out, int out_size, void* d_ws, size_t ws_size,
                              hipStream_t stream) {
  const float* x    = (const float*)d_in[0];
  const int* esrc   = (const int*)d_in[1];
  const int* edst   = (const int*)d_in[2];
  const int* batch  = (const int*)d_in[3];
  const float* Wl[3]  = {(const float*)d_in[5],  (const float*)d_in[11], (const float*)d_in[17]};
  const float* Wr[3]  = {(const float*)d_in[6],  (const float*)d_in[12], (const float*)d_in[18]};
  const float* att[3] = {(const float*)d_in[7],  (const float*)d_in[13], (const float*)d_in[19]};
  const float* bia[3] = {(const float*)d_in[8],  (const float*)d_in[14], (const float*)d_in[20]};
  const float* gam[3] = {(const float*)d_in[9],  (const float*)d_in[15], (const float*)d_in[21]};
  const float* bet[3] = {(const float*)d_in[10], (const float*)d_in[16], (const float*)d_in[22]};
  const float* Wmu = (const float*)d_in[23];
  const float* bmu = (const float*)d_in[24];
  const float* Wlv = (const float*)d_in[25];
  const float* blv = (const float*)d_in[26];
  float* out = (float*)d_out;

  const int N = in_sizes[0] / 64;
  const int E = in_sizes[1];
  const int G = out_size / 128;
  const int nbk = (N + 255) / 256;

  char* p = (char*)d_ws;
  auto alloc = [&](size_t bytes) -> void* {
    void* r = (void*)p;
    p += (bytes + 255) & ~(size_t)255;
    return r;
  };
  // zero-init region first (one memset: bktcnt + bnsums + pool + ccur + colb)
  int*   bktcnt  = (int*)alloc(256 * 4);
  float* bnsums  = (float*)alloc(3 * NSHARD * 128 * 4);
  float* pool    = (float*)alloc((size_t)G * 64 * 4);
  int*   ccur    = (int*)alloc(256);
  int*   colb    = (int*)alloc(((size_t)E + 3 * (size_t)N + 64) * 4); // 4-padded rows + zero tail
  char*  zend    = p;
  unsigned char* xlb = (unsigned char*)alloc((size_t)N * 256);
  unsigned char* xrb = (unsigned char*)alloc((size_t)N * 256);
  float* hA     = (float*)alloc((size_t)N * 64 * 4);
  float* hB     = (float*)alloc((size_t)N * 64 * 4);
  float* gat    = (float*)alloc((size_t)N * 64 * 4);
  int*   rowptr = (int*)alloc((size_t)(N + 1) * 4);
  int2*  ebuf   = (int2*)alloc((size_t)nbk * ECAP * 8);
  unsigned short* wt = (unsigned short*)alloc(6 * 16384 * 2);

  const int nbGat = (N + 3) / 4;
  const int ntiles = (N + 31) / 32;
  const float inv_n = 1.f / (float)N;

  hipMemsetAsync(bktcnt, 0, (size_t)(zend - (char*)bktcnt), stream);

  // ---- CSR build: W-prep + single-pass bucket place (fused) ----
  k_prep<<<384 + NEB, 256, 0, stream>>>(Wl[0], Wr[0], Wl[1], Wr[1], Wl[2], Wr[2], wt,
                                        esrc, edst, bktcnt, ebuf, E, N);

  float* bns0 = bnsums;
  float* bns1 = bnsums + NSHARD * 128;
  float* bns2 = bnsums + 2 * NSHARD * 128;

  // ---- layer 0 (y=2 partition finalizes CSR concurrently with the GEMM) ----
  k_mm0<<<dim3(512, 3), 256, 0, stream>>>(x, wt, xlb, xrb, ebuf, bktcnt, rowptr, colb,
                                          ccur, N, ntiles);
  k_gat0<<<nbGat, 256, 0, stream>>>(xlb, xrb, att[0], bia[0], rowptr, colb, gat, bns0, N);
  // ---- layer 1 (applies h0 = gelu(bn0(gat0))) ----
  k_mm1<<<dim3(512, 2), 256, 0, stream>>>(gat, bns0, gam[0], bet[0], hA,
                                          wt + 2 * 16384, xlb, xrb, N, ntiles, inv_n);
  k_gat1<<<nbGat, 256, 0, stream>>>(xlb, xrb, att[1], bia[1], rowptr, colb, gat, bns1, N);
  // ---- layer 2 (applies h1 = gelu(bn1(gat1)) + h0) ----
  k_mm2<<<dim3(512, 2), 256, 0, stream>>>(gat, bns1, gam[1], bet[1], hA, hB,
                                          wt + 4 * 16384, xlb, xrb, N, ntiles, inv_n);
  k_gat2<<<nbGat, 256, 0, stream>>>(xlb, xrb, att[2], bia[2], rowptr, colb, gat, bns2, N);
  // ---- final: h2 = gelu(bn2(gat2)) + h1 -> pool ----
  k_bn_pool<<<(N + 127) / 128, 256, 0, stream>>>(gat, bns2, gam[2], bet[2], hB, batch, pool,
                                                 N, inv_n);
  k_head<<<G, 64, 0, stream>>>(pool, Wmu, bmu, Wlv, blv, out, G);
}

// Round 14
// 365.180 us; speedup vs baseline: 1.1963x; 1.0085x over previous
//
#include <hip/hip_runtime.h>
#include <math.h>

typedef __attribute__((ext_vector_type(8))) short bf16x8;
typedef __attribute__((ext_vector_type(4))) float f32x4;
typedef __attribute__((ext_vector_type(2))) float f32x2;

static __device__ __forceinline__ unsigned short f2bf(float f) {
  unsigned u = __float_as_uint(f);
  unsigned r = (u + 0x7FFF + ((u >> 16) & 1)) >> 16; // RNE
  return (unsigned short)r;
}

// DPP add: x += lane-permuted x. bound_ctrl=true + bijective ctrl (quad_perm /
// row_half_mirror) lets GCNDPPCombine fold the mov_dpp into v_add_f32_dpp.
#define DPP_ADD(x, ctrl) \
  ((x) + __int_as_float(__builtin_amdgcn_update_dpp(0, __float_as_int(x), (ctrl), 0xf, 0xf, true)))

#define NSHARD 64
#define NEB 256   // edge-chunk blocks for the place pass
#define ECAP 6144 // fixed bucket stride in ebuf (mean fill 4096, sigma 64)

// ---------------- W-prep + single-pass bucket place ----------------

__global__ __launch_bounds__(256) void k_prep(const float* __restrict__ W0, const float* __restrict__ W1,
                                              const float* __restrict__ W2, const float* __restrict__ W3,
                                              const float* __restrict__ W4, const float* __restrict__ W5,
                                              unsigned short* __restrict__ wt,
                                              const int* __restrict__ esrc,
                                              const int* __restrict__ edst,
                                              int* __restrict__ bktcnt,
                                              int2* __restrict__ ebuf, int E, int N) {
  if (blockIdx.x < 384) {
    int gid = blockIdx.x * 256 + threadIdx.x; // 6 * 16384
    int m = gid >> 14;
    int r = gid & 16383;
    int k = r >> 8;
    int n = r & 255;
    const float* W = (m == 0) ? W0 : (m == 1) ? W1 : (m == 2) ? W2
                   : (m == 3) ? W3 : (m == 4) ? W4 : W5;
    wt[(size_t)m * 16384 + n * 64 + k] = f2bf(W[k * 256 + n]);
    return;
  }
  const int b = blockIdx.x - 384;
  const int nbk = (N + 255) >> 8;
  __shared__ int cnt[256], base[256];
  cnt[threadIdx.x] = 0;
  __syncthreads();
  const int chunk = (E + NEB - 1) / NEB;
  const int e0 = b * chunk, e1 = min(e0 + chunk, E);
  for (int e = e0 + threadIdx.x; e < e1; e += 256) atomicAdd(&cnt[edst[e] >> 8], 1);
  __syncthreads();
  if (threadIdx.x < nbk && cnt[threadIdx.x])
    base[threadIdx.x] = atomicAdd(&bktcnt[threadIdx.x], cnt[threadIdx.x]);
  cnt[threadIdx.x] = 0; // reuse as local cursor (own-index only before sync)
  __syncthreads();
  for (int e = e0 + threadIdx.x; e < e1; e += 256) {
    int d = edst[e];
    int bk = d >> 8;
    int p = base[bk] + atomicAdd(&cnt[bk], 1);
    ebuf[(size_t)bk * ECAP + p] = make_int2(d, esrc[e]);
  }
}

// ---------------- pass2 (y=1 of k_mm0): per-bucket CSR finalize, 4-padded ----------------
// Per-node lists padded to %4 (pad slots stay 0 from memset -> safe gather of row 0,
// masked by deg). rowptr packs pos|deg<<22. colb space reserved via global cursor.

static __device__ __forceinline__ void csr_pass2(const int2* __restrict__ ebuf,
                                                 const int* __restrict__ bktcnt,
                                                 int* __restrict__ rowptr,
                                                 int* __restrict__ colb,
                                                 int* __restrict__ ccur,
                                                 int N, char* smem) {
  const int b = blockIdx.x;
  const int nbk = (N + 255) >> 8;
  if (b >= nbk) return;
  int* hist = (int*)smem;          // 256
  int* s = (int*)smem + 256;       // 256 (scan buffer)
  int* sb = (int*)smem + 512;      // 1 (bucket colb-base broadcast)
  const int tid = threadIdx.x;
  const int lo = b * ECAP;
  const int hi = lo + bktcnt[b];
  hist[tid] = 0;
  __syncthreads();
  for (int i = lo + tid; i < hi; i += 256) atomicAdd(&hist[ebuf[i].x & 255], 1);
  __syncthreads();
  int deg = hist[tid];
  int pd = (deg + 3) & ~3;
  s[tid] = pd;
  __syncthreads();
  for (int off = 1; off < 256; off <<= 1) {
    int t = (tid >= off) ? s[tid - off] : 0;
    __syncthreads();
    s[tid] += t;
    __syncthreads();
  }
  if (tid == 255) sb[0] = atomicAdd(ccur, s[255]);
  __syncthreads();
  int pos = sb[0] + s[tid] - pd; // exclusive prefix of padded degrees
  int node = (b << 8) + tid;
  if (node < N) rowptr[node] = (int)((unsigned)pos | ((unsigned)deg << 22));
  hist[tid] = pos; // reuse as global cursor
  __syncthreads();
  for (int i = lo + tid; i < hi; i += 256) {
    int2 e = ebuf[i];
    int p = atomicAdd(&hist[e.x & 255], 1);
    colb[p] = e.y << 8; // byte offset into fp8 rows (256 fp8 = 256 B)
  }
}

// ---------------- MFMA dual-B GEMM + fused BN/GELU/residual producer ----------------
// ONE block computes BOTH Wl and Wr outputs per tile: A load + BN/GELU/erf +
// bf16-convert + LDS staging happen ONCE (was duplicated across y=0/y=1 blocks).
// Bs holds Wl||Wr (512 rows x 64, contiguous in wt since Wr starts at 16384 =
// 256*64). LDS 68KB -> 2 blocks/CU; mm is a streaming pipelined kernel, tolerant
// of lower occupancy. Gather copies stored fp8 e4m3; hout keeps f32 quality.

static __device__ __forceinline__ void mm_gemm(const float* __restrict__ src,
                                               const float* __restrict__ bnsums,
                                               const float* __restrict__ g,
                                               const float* __restrict__ be,
                                               const float* __restrict__ resid,
                                               float* __restrict__ hout,
                                               const unsigned short* __restrict__ wt,
                                               unsigned char* __restrict__ xlb,
                                               unsigned char* __restrict__ xrb,
                                               int N, int ntiles, float inv_n,
                                               char* smem) {
  unsigned short* Bs = (unsigned short*)smem;           // 512*64 shorts (Wl||Wr), swizzled
  unsigned short* Ah = (unsigned short*)(smem + 65536); // 32*64
  const int t = threadIdx.x;

  const int wave = t >> 6, lane = t & 63;
  const int rw = (wave & 1) * 16, cw = (wave >> 1) * 128;
  const int m15 = lane & 15, quad = lane >> 4;
  const int arow = t >> 3, ac0 = (t & 7) * 8;
  const int aoff = arow * 64 + (((t & 7) ^ (arow & 7)) << 3); // swizzled A slot

  float scale[8], shift[8];
  if (bnsums) {
    float* stat = (float*)smem; // overlay: consumed before Bs fill
    if (t < 128) {
      float a = 0.f;
#pragma unroll
      for (int sd = 0; sd < NSHARD; ++sd) a += bnsums[sd * 128 + t];
      stat[t] = a;
    }
    __syncthreads();
#pragma unroll
    for (int i = 0; i < 8; ++i) {
      int c = ac0 + i;
      float mu = stat[c] * inv_n;
      float var = stat[64 + c] * inv_n - mu * mu;
      float rs = rsqrtf(var + 1e-5f) * g[c];
      scale[i] = rs;
      shift[i] = be[c] - mu * rs;
    }
    __syncthreads(); // stat reads done before Bs fill overwrites
  }

  // fill Wl||Wr: rows 0..255 = Wl cols, rows 256..511 = Wr cols; both live at
  // wt + n*64 (Wr block starts at 16384 = 256*64). Swizzle key (n>>3)&7 == m15&7
  // for every row the MFMA loop reads (cw>>3 and 256>>3 are multiples of 8).
#pragma unroll
  for (int j = 0; j < 16; ++j) {
    int cidx = t + 256 * j;
    int n = cidx >> 3, gg = cidx & 7;
    *(bf16x8*)&Bs[n * 64 + (((gg ^ ((n >> 3) & 7))) << 3)] =
        *(const bf16x8*)(wt + (size_t)n * 64 + gg * 8);
  }

  const bool wr_h = (hout != nullptr);
  const int gstride = gridDim.x;

  float4 a0, a1, rv0, rv1;
  auto loadA = [&](int tl, float4& x0, float4& x1, float4& r0v, float4& r1v) {
    x0 = make_float4(0.f, 0.f, 0.f, 0.f);
    x1 = make_float4(0.f, 0.f, 0.f, 0.f);
    r0v = make_float4(0.f, 0.f, 0.f, 0.f);
    r1v = make_float4(0.f, 0.f, 0.f, 0.f);
    int gr = tl * 32 + arow;
    if (tl < ntiles && gr < N) {
      x0 = *(const float4*)(src + (size_t)gr * 64 + ac0);
      x1 = *(const float4*)(src + (size_t)gr * 64 + ac0 + 4);
      if (resid) {
        r0v = *(const float4*)(resid + (size_t)gr * 64 + ac0);
        r1v = *(const float4*)(resid + (size_t)gr * 64 + ac0 + 4);
      }
    }
  };
  loadA(blockIdx.x, a0, a1, rv0, rv1);

  for (int tile = blockIdx.x; tile < ntiles; tile += gstride) {
    int r0 = tile * 32;
    int gr = r0 + arow;
    {
      float vs[8] = {a0.x, a0.y, a0.z, a0.w, a1.x, a1.y, a1.z, a1.w};
      if (bnsums) {
        float rv[8] = {rv0.x, rv0.y, rv0.z, rv0.w, rv1.x, rv1.y, rv1.z, rv1.w};
#pragma unroll
        for (int i = 0; i < 8; ++i) {
          float v = fmaf(vs[i], scale[i], shift[i]);
          float ge = 0.5f * v * (1.f + erff(v * 0.70710678118654752f));
          vs[i] = ge + rv[i];
        }
        if (wr_h && gr < N) {
          float4 o0 = {vs[0], vs[1], vs[2], vs[3]};
          float4 o1 = {vs[4], vs[5], vs[6], vs[7]};
          *(float4*)(hout + (size_t)gr * 64 + ac0) = o0;
          *(float4*)(hout + (size_t)gr * 64 + ac0 + 4) = o1;
        }
      }
      bf16x8 hi8;
#pragma unroll
      for (int i = 0; i < 8; ++i) hi8[i] = (short)f2bf(vs[i]);
      *(bf16x8*)&Ah[aoff] = hi8;
    }
    __syncthreads();

    // software pipeline: issue next tile's A loads under MFMA + epilogue
    loadA(tile + gstride, a0, a1, rv0, rv1);

    f32x4 accL[8], accR[8];
#pragma unroll
    for (int s = 0; s < 8; ++s) {
      accL[s] = (f32x4){0.f, 0.f, 0.f, 0.f};
      accR[s] = (f32x4){0.f, 0.f, 0.f, 0.f};
    }
    const int xq = m15 & 7;
#pragma unroll
    for (int kk = 0; kk < 64; kk += 32) {
      const int ga = (((kk >> 3) + quad) ^ xq) << 3;
      bf16x8 ah = *(const bf16x8*)&Ah[(rw + m15) * 64 + ga];
#pragma unroll
      for (int s = 0; s < 8; ++s) {
        bf16x8 bl = *(const bf16x8*)&Bs[(cw + m15 * 8 + s) * 64 + ga];
        accL[s] = __builtin_amdgcn_mfma_f32_16x16x32_bf16(ah, bl, accL[s], 0, 0, 0);
        bf16x8 br = *(const bf16x8*)&Bs[(256 + cw + m15 * 8 + s) * 64 + ga];
        accR[s] = __builtin_amdgcn_mfma_f32_16x16x32_bf16(ah, br, accR[s], 0, 0, 0);
      }
    }
#pragma unroll
    for (int r = 0; r < 4; ++r) {
      int row_g = r0 + rw + quad * 4 + r;
      if (row_g < N) {
        int w0 = __builtin_amdgcn_cvt_pk_fp8_f32(accL[0][r], accL[1][r], 0, false);
        w0 = __builtin_amdgcn_cvt_pk_fp8_f32(accL[2][r], accL[3][r], w0, true);
        int w1 = __builtin_amdgcn_cvt_pk_fp8_f32(accL[4][r], accL[5][r], 0, false);
        w1 = __builtin_amdgcn_cvt_pk_fp8_f32(accL[6][r], accL[7][r], w1, true);
        uint2 oL = {(unsigned)w0, (unsigned)w1};
        *(uint2*)(xlb + (size_t)row_g * 256 + cw + m15 * 8) = oL;
        int w2 = __builtin_amdgcn_cvt_pk_fp8_f32(accR[0][r], accR[1][r], 0, false);
        w2 = __builtin_amdgcn_cvt_pk_fp8_f32(accR[2][r], accR[3][r], w2, true);
        int w3 = __builtin_amdgcn_cvt_pk_fp8_f32(accR[4][r], accR[5][r], 0, false);
        w3 = __builtin_amdgcn_cvt_pk_fp8_f32(accR[6][r], accR[7][r], w3, true);
        uint2 oR = {(unsigned)w2, (unsigned)w3};
        *(uint2*)(xrb + (size_t)row_g * 256 + cw + m15 * 8) = oR;
      }
    }
    __syncthreads();
  }
}

__global__ __launch_bounds__(256, 2) void k_mm0(const float* __restrict__ src,
                                                const unsigned short* __restrict__ wt,
                                                unsigned char* __restrict__ xlb,
                                                unsigned char* __restrict__ xrb,
                                                const int2* __restrict__ ebuf,
                                                const int* __restrict__ bktcnt,
                                                int* __restrict__ rowptr,
                                                int* __restrict__ colb,
                                                int* __restrict__ ccur,
                                                int N, int ntiles) {
  __shared__ __align__(16) char smem[69632];
  if (blockIdx.y == 1) {
    csr_pass2(ebuf, bktcnt, rowptr, colb, ccur, N, smem);
    return;
  }
  mm_gemm(src, nullptr, nullptr, nullptr, nullptr, nullptr, wt, xlb, xrb, N, ntiles, 0.f, smem);
}

__global__ __launch_bounds__(256, 2) void k_mm1(const float* __restrict__ src,
                                                const float* __restrict__ bnsums,
                                                const float* __restrict__ g,
                                                const float* __restrict__ be,
                                                float* __restrict__ hout,
                                                const unsigned short* __restrict__ wt,
                                                unsigned char* __restrict__ xlb,
                                                unsigned char* __restrict__ xrb,
                                                int N, int ntiles, float inv_n) {
  __shared__ __align__(16) char smem[69632];
  mm_gemm(src, bnsums, g, be, nullptr, hout, wt, xlb, xrb, N, ntiles, inv_n, smem);
}

__global__ __launch_bounds__(256, 2) void k_mm2(const float* __restrict__ src,
                                                const float* __restrict__ bnsums,
                                                const float* __restrict__ g,
                                                const float* __restrict__ be,
                                                const float* __restrict__ resid,
                                                float* __restrict__ hout,
                                                const unsigned short* __restrict__ wt,
                                                unsigned char* __restrict__ xlb,
                                                unsigned char* __restrict__ xrb,
                                                int N, int ntiles, float inv_n) {
  __shared__ __align__(16) char smem[69632];
  mm_gemm(src, bnsums, g, be, resid, hout, wt, xlb, xrb, N, ntiles, inv_n, smem);
}

// ---------------- GATv2: 2-edges-per-wave, fp8 gather rows, f32 math ----
// (round-10 form — measured best at 57.7 us; deeper prefetch and f16/packed
// variants all regressed or were null)

static __device__ __forceinline__ void gat_body(const unsigned char* __restrict__ xlb,
                                                const unsigned char* __restrict__ xrb,
                                                const float* __restrict__ att,
                                                const float* __restrict__ bias,
                                                const int* __restrict__ rowptr,
                                                const int* __restrict__ colb,
                                                float* __restrict__ out,
                                                float* __restrict__ bnsums, int N) {
  __shared__ float sres[4][64];
  const int lane = threadIdx.x & 63;
  const int wv = threadIdx.x >> 6;
  const int half = lane >> 5; // which edge of the pair this lane serves
  const int l5 = lane & 31;
  const int node0 = blockIdx.x * 4 + wv;
  const bool valid = node0 < N;
  const int node = __builtin_amdgcn_readfirstlane(valid ? node0 : 0); // wave-uniform
  const int rp = rowptr[node];
  const int beg = rp & 0x3FFFFF;
  const int deg = (int)(((unsigned)rp) >> 22);
  const int end = valid ? beg + deg : beg;

  const unsigned char* xl = xlb; // wave-uniform base -> SADDR form
  const unsigned lb = (unsigned)l5 * 8u;

  auto sel = [&](int a, int b) { return (unsigned)(half ? b : a); };

  int4 c0 = *(const int4*)(colb + beg);     // edges 0..3 (16B-aligned: beg%4==0)
  int4 c1 = *(const int4*)(colb + beg + 4); // edges 4..7
  const unsigned self_off = (unsigned)(node << 8);
  uint2 vbs = *(const uint2*)(xl + self_off + lb);
  uint2 pd0 = *(const uint2*)(xl + (sel(c0.x, c0.y) + lb));
  uint2 pd1 = *(const uint2*)(xl + (sel(c0.z, c0.w) + lb));
  uint2 pt0 = *(const uint2*)(xl + (sel(c1.x, c1.y) + lb));
  uint2 pt1 = *(const uint2*)(xl + (sel(c1.z, c1.w) + lb));
  int4 cn = *(const int4*)(colb + beg + 8); // offsets for edges 8..11

  float4 aa = *(const float4*)(att + l5 * 8);
  float4 ab = *(const float4*)(att + l5 * 8 + 4);
  const float LOG2E = 1.4426950408889634f;
  const f32x2 a01 = {aa.x * LOG2E, aa.y * LOG2E};
  const f32x2 a23 = {aa.z * LOG2E, aa.w * LOG2E};
  const f32x2 a45 = {ab.x * LOG2E, ab.y * LOG2E};
  const f32x2 a67 = {ab.z * LOG2E, ab.w * LOG2E};
  const f32x2 c02 = {0.2f, 0.2f};
  uint2 xru = *(const uint2*)(xrb + self_off + lb);
  const f32x2 xr01 = __builtin_amdgcn_cvt_pk_f32_fp8((int)xru.x, false);
  const f32x2 xr23 = __builtin_amdgcn_cvt_pk_f32_fp8((int)xru.x, true);
  const f32x2 xr45 = __builtin_amdgcn_cvt_pk_f32_fp8((int)xru.y, false);
  const f32x2 xr67 = __builtin_amdgcn_cvt_pk_f32_fp8((int)xru.y, true);

  // score over 8 channels/lane, reduced across the 8-lane head group (both
  // halves reduce their own edge). Returns per-(head,edge) score; also yields
  // the converted channel values for the accumulation.
  auto score = [&](uint2 vb, f32x2& v01, f32x2& v23, f32x2& v45, f32x2& v67) -> float {
    v01 = __builtin_amdgcn_cvt_pk_f32_fp8((int)vb.x, false);
    v23 = __builtin_amdgcn_cvt_pk_f32_fp8((int)vb.x, true);
    v45 = __builtin_amdgcn_cvt_pk_f32_fp8((int)vb.y, false);
    v67 = __builtin_amdgcn_cvt_pk_f32_fp8((int)vb.y, true);
    f32x2 s01 = v01 + xr01;
    f32x2 s23 = v23 + xr23;
    f32x2 s45 = v45 + xr45;
    f32x2 s67 = v67 + xr67;
    s01 = __builtin_elementwise_max(s01, s01 * c02);
    s23 = __builtin_elementwise_max(s23, s23 * c02);
    s45 = __builtin_elementwise_max(s45, s45 * c02);
    s67 = __builtin_elementwise_max(s67, s67 * c02);
    f32x2 q = s01 * a01;
    q = __builtin_elementwise_fma(s23, a23, q);
    q = __builtin_elementwise_fma(s45, a45, q);
    q = __builtin_elementwise_fma(s67, a67, q);
    float p = q.x + q.y;
    p = DPP_ADD(p, 0xB1);  // quad_perm [1,0,3,2]
    p = DPP_ADD(p, 0x4E);  // quad_perm [2,3,0,1]
    p = DPP_ADD(p, 0x141); // row_half_mirror -> 8-lane (head) group sum
    return p;
  };

  f32x2 sv01, sv23, sv45, sv67;
  const float m = score(vbs, sv01, sv23, sv45, sv67); // self score (identical in both halves)

  const float hsel = half ? 0.f : 1.f; // self counted once (half 0)
  float lsum = hsel;
  const f32x2 hs2 = {hsel, hsel};
  f32x2 o01 = sv01 * hs2, o23 = sv23 * hs2, o45 = sv45 * hs2, o67 = sv67 * hs2;

  auto proc = [&](uint2 vb, int ebase) {
    f32x2 v01, v23, v45, v67;
    float p = score(vb, v01, v23, v45, v67);
    float w = __builtin_amdgcn_exp2f(fminf(p - m, 126.f));
    w = (ebase + half < end) ? w : 0.f;
    lsum += w;
    f32x2 w2 = {w, w};
    o01 = __builtin_elementwise_fma(w2, v01, o01);
    o23 = __builtin_elementwise_fma(w2, v23, o23);
    o45 = __builtin_elementwise_fma(w2, v45, o45);
    o67 = __builtin_elementwise_fma(w2, v67, o67);
  };

  for (int e = beg; e < end; e += 4) {
    uint2 pu0 = *(const uint2*)(xl + (sel(cn.x, cn.y) + lb));
    uint2 pu1 = *(const uint2*)(xl + (sel(cn.z, cn.w) + lb));
    cn = *(const int4*)(colb + e + 12);
    proc(pd0, e);
    proc(pd1, e + 2);
    pd0 = pt0; pd1 = pt1;
    pt0 = pu0; pt1 = pu1;
  }

  // per-(head) denominator: sum across the two edge-halves, then normalize
  lsum += __shfl_xor(lsum, 32, 64);
  float inv = __builtin_amdgcn_rcpf(lsum);
  float r[8] = {o01.x * inv, o01.y * inv, o23.x * inv, o23.y * inv,
                o45.x * inv, o45.y * inv, o67.x * inv, o67.y * inv};
#pragma unroll
  for (int j = 0; j < 8; ++j) {
    r[j] += __shfl_xor(r[j], 8, 64);  // head pairs
    r[j] += __shfl_xor(r[j], 16, 64); // all 4 heads
    r[j] += __shfl_xor(r[j], 32, 64); // edge halves
  }
  if (lane < 8) {
    float4 res0 = {0.f, 0.f, 0.f, 0.f}, res1 = {0.f, 0.f, 0.f, 0.f};
    if (valid) {
      float4 b0 = *(const float4*)(bias + lane * 8);
      float4 b1 = *(const float4*)(bias + lane * 8 + 4);
      res0.x = 0.25f * r[0] + b0.x;
      res0.y = 0.25f * r[1] + b0.y;
      res0.z = 0.25f * r[2] + b0.z;
      res0.w = 0.25f * r[3] + b0.w;
      res1.x = 0.25f * r[4] + b1.x;
      res1.y = 0.25f * r[5] + b1.y;
      res1.z = 0.25f * r[6] + b1.z;
      res1.w = 0.25f * r[7] + b1.w;
      *(float4*)(out + (size_t)node * 64 + lane * 8) = res0;
      *(float4*)(out + (size_t)node * 64 + lane * 8 + 4) = res1;
    }
    *(float4*)&sres[wv][lane * 8] = res0;
    *(float4*)&sres[wv][lane * 8 + 4] = res1;
  }
  __syncthreads();
  if (threadIdx.x < 64) {
    int c = threadIdx.x;
    float s0 = sres[0][c], s1 = sres[1][c], s2 = sres[2][c], s3 = sres[3][c];
    float* bs = bnsums + (size_t)(blockIdx.x & (NSHARD - 1)) * 128;
    atomicAdd(&bs[c], s0 + s1 + s2 + s3);
    atomicAdd(&bs[64 + c], s0 * s0 + s1 * s1 + s2 * s2 + s3 * s3);
  }
}

__global__ __launch_bounds__(256) void k_gat0(const unsigned char* __restrict__ xlb,
                                              const unsigned char* __restrict__ xrb,
                                              const float* __restrict__ att,
                                              const float* __restrict__ bias,
                                              const int* __restrict__ rowptr,
                                              const int* __restrict__ colb,
                                              float* __restrict__ out,
                                              float* __restrict__ bnsums, int N) {
  gat_body(xlb, xrb, att, bias, rowptr, colb, out, bnsums, N);
}
__global__ __launch_bounds__(256) void k_gat1(const unsigned char* __restrict__ xlb,
                                              const unsigned char* __restrict__ xrb,
                                              const float* __restrict__ att,
                                              const float* __restrict__ bias,
                                              const int* __restrict__ rowptr,
                                              const int* __restrict__ colb,
                                              float* __restrict__ out,
                                              float* __restrict__ bnsums, int N) {
  gat_body(xlb, xrb, att, bias, rowptr, colb, out, bnsums, N);
}
__global__ __launch_bounds__(256) void k_gat2(const unsigned char* __restrict__ xlb,
                                              const unsigned char* __restrict__ xrb,
                                              const float* __restrict__ att,
                                              const float* __restrict__ bias,
                                              const int* __restrict__ rowptr,
                                              const int* __restrict__ colb,
                                              float* __restrict__ out,
                                              float* __restrict__ bnsums, int N) {
  gat_body(xlb, xrb, att, bias, rowptr, colb, out, bnsums, N);
}

// ---------------- final: collapse shards -> BN+GELU+residual -> run-batched pool ----------------

__global__ __launch_bounds__(256) void k_bn_pool(const float* __restrict__ gat,
                                                 const float* __restrict__ bnsums,
                                                 const float* __restrict__ g,
                                                 const float* __restrict__ be,
                                                 const float* __restrict__ resid,
                                                 const int* __restrict__ batch,
                                                 float* __restrict__ pool,
                                                 int N, float inv_n) {
  __shared__ float sc[64], sh[64];
  if (threadIdx.x < 64) {
    int c = threadIdx.x;
    float s = 0.f, q = 0.f;
    for (int sd = 0; sd < NSHARD; ++sd) {
      s += bnsums[sd * 128 + c];
      q += bnsums[sd * 128 + 64 + c];
    }
    float mu = s * inv_n;
    float var = q * inv_n - mu * mu;
    float rs = rsqrtf(var + 1e-5f) * g[c];
    sc[c] = rs;
    sh[c] = be[c] - mu * rs;
  }
  __syncthreads();
  const int c = threadIdx.x & 63;
  const int wv = threadIdx.x >> 6;
  int n0 = (blockIdx.x * 4 + wv) * 32;
  if (n0 >= N) return;
  int n1 = min(n0 + 32, N);
  int curg = batch[n0]; // wave-uniform (batch sorted)
  float acc = 0.f;
  for (int n = n0; n < n1; ++n) {
    int b = batch[n];
    if (b != curg) {
      atomicAdd(&pool[(size_t)curg * 64 + c], acc);
      acc = 0.f;
      curg = b;
    }
    float v = fmaf(gat[(size_t)n * 64 + c], sc[c], sh[c]);
    float ge = 0.5f * v * (1.f + erff(v * 0.70710678118654752f));
    acc += ge + resid[(size_t)n * 64 + c];
  }
  atomicAdd(&pool[(size_t)curg * 64 + c], acc);
}

// ---------------- heads ----------------

__global__ void k_head(const float* __restrict__ pool, const float* __restrict__ Wmu,
                       const float* __restrict__ bmu, const float* __restrict__ Wlv,
                       const float* __restrict__ blv, float* __restrict__ out, int G) {
  int g = blockIdx.x;
  int c = threadIdx.x; // 64 threads
  __shared__ float row[64];
  row[c] = pool[(size_t)g * 64 + c];
  __syncthreads();
  float am = 0.f, al = 0.f;
  for (int k = 0; k < 64; ++k) {
    float r = row[k];
    am = fmaf(r, Wmu[k * 64 + c], am);
    al = fmaf(r, Wlv[k * 64 + c], al);
  }
  out[(size_t)g * 64 + c] = am + bmu[c];
  out[(size_t)G * 64 + (size_t)g * 64 + c] = al + blv[c];
}

// ---------------- launch ----------------

extern "C" void kernel_launch(void* const* d_in, const int* in_sizes, int n_in,
                              void* d_out, int out_size, void* d_ws, size_t ws_size,
                              hipStream_t stream) {
  const float* x    = (const float*)d_in[0];
  const int* esrc   = (const int*)d_in[1];
  const int* edst   = (const int*)d_in[2];
  const int* batch  = (const int*)d_in[3];
  const float* Wl[3]  = {(const float*)d_in[5],  (const float*)d_in[11], (const float*)d_in[17]};
  const float* Wr[3]  = {(const float*)d_in[6],  (const float*)d_in[12], (const float*)d_in[18]};
  const float* att[3] = {(const float*)d_in[7],  (const float*)d_in[13], (const float*)d_in[19]};
  const float* bia[3] = {(const float*)d_in[8],  (const float*)d_in[14], (const float*)d_in[20]};
  const float* gam[3] = {(const float*)d_in[9],  (const float*)d_in[15], (const float*)d_in[21]};
  const float* bet[3] = {(const float*)d_in[10], (const float*)d_in[16], (const float*)d_in[22]};
  const float* Wmu = (const float*)d_in[23];
  const float* bmu = (const float*)d_in[24];
  const float* Wlv = (const float*)d_in[25];
  const float* blv = (const float*)d_in[26];
  float* out = (float*)d_out;

  const int N = in_sizes[0] / 64;
  const int E = in_sizes[1];
  const int G = out_size / 128;
  const int nbk = (N + 255) / 256;

  char* p = (char*)d_ws;
  auto alloc = [&](size_t bytes) -> void* {
    void* r = (void*)p;
    p += (bytes + 255) & ~(size_t)255;
    return r;
  };
  // zero-init region first (one memset: bktcnt + bnsums + pool + ccur + colb)
  int*   bktcnt  = (int*)alloc(256 * 4);
  float* bnsums  = (float*)alloc(3 * NSHARD * 128 * 4);
  float* pool    = (float*)alloc((size_t)G * 64 * 4);
  int*   ccur    = (int*)alloc(256);
  int*   colb    = (int*)alloc(((size_t)E + 3 * (size_t)N + 64) * 4); // 4-padded rows + zero tail
  char*  zend    = p;
  unsigned char* xlb = (unsigned char*)alloc((size_t)N * 256);
  unsigned char* xrb = (unsigned char*)alloc((size_t)N * 256);
  float* hA     = (float*)alloc((size_t)N * 64 * 4);
  float* hB     = (float*)alloc((size_t)N * 64 * 4);
  float* gat    = (float*)alloc((size_t)N * 64 * 4);
  int*   rowptr = (int*)alloc((size_t)(N + 1) * 4);
  int2*  ebuf   = (int2*)alloc((size_t)nbk * ECAP * 8);
  unsigned short* wt = (unsigned short*)alloc(6 * 16384 * 2);

  const int nbGat = (N + 3) / 4;
  const int ntiles = (N + 31) / 32;
  const float inv_n = 1.f / (float)N;

  hipMemsetAsync(bktcnt, 0, (size_t)(zend - (char*)bktcnt), stream);

  // ---- CSR build: W-prep + single-pass bucket place (fused) ----
  k_prep<<<384 + NEB, 256, 0, stream>>>(Wl[0], Wr[0], Wl[1], Wr[1], Wl[2], Wr[2], wt,
                                        esrc, edst, bktcnt, ebuf, E, N);

  float* bns0 = bnsums;
  float* bns1 = bnsums + NSHARD * 128;
  float* bns2 = bnsums + 2 * NSHARD * 128;

  // ---- layer 0 (y=1 partition finalizes CSR concurrently with the GEMM) ----
  k_mm0<<<dim3(512, 2), 256, 0, stream>>>(x, wt, xlb, xrb, ebuf, bktcnt, rowptr, colb,
                                          ccur, N, ntiles);
  k_gat0<<<nbGat, 256, 0, stream>>>(xlb, xrb, att[0], bia[0], rowptr, colb, gat, bns0, N);
  // ---- layer 1 (applies h0 = gelu(bn0(gat0))) ----
  k_mm1<<<dim3(512, 1), 256, 0, stream>>>(gat, bns0, gam[0], bet[0], hA,
                                          wt + 2 * 16384, xlb, xrb, N, ntiles, inv_n);
  k_gat1<<<nbGat, 256, 0, stream>>>(xlb, xrb, att[1], bia[1], rowptr, colb, gat, bns1, N);
  // ---- layer 2 (applies h1 = gelu(bn1(gat1)) + h0) ----
  k_mm2<<<dim3(512, 1), 256, 0, stream>>>(gat, bns1, gam[1], bet[1], hA, hB,
                                          wt + 4 * 16384, xlb, xrb, N, ntiles, inv_n);
  k_gat2<<<nbGat, 256, 0, stream>>>(xlb, xrb, att[2], bia[2], rowptr, colb, gat, bns2, N);
  // ---- final: h2 = gelu(bn2(gat2)) + h1 -> pool ----
  k_bn_pool<<<(N + 127) / 128, 256, 0, stream>>>(gat, bns2, gam[2], bet[2], hB, batch, pool,
                                                 N, inv_n);
  k_head<<<G, 64, 0, stream>>>(pool, Wmu, bmu, Wlv, blv, out, G);
}

// Round 15
// 356.146 us; speedup vs baseline: 1.2267x; 1.0254x over previous
//
#include <hip/hip_runtime.h>
#include <math.h>

typedef __attribute__((ext_vector_type(8))) short bf16x8;
typedef __attribute__((ext_vector_type(4))) float f32x4;
typedef __attribute__((ext_vector_type(2))) float f32x2;

static __device__ __forceinline__ unsigned short f2bf(float f) {
  unsigned u = __float_as_uint(f);
  unsigned r = (u + 0x7FFF + ((u >> 16) & 1)) >> 16; // RNE
  return (unsigned short)r;
}

// DPP add: x += lane-permuted x. bound_ctrl=true + bijective ctrl (quad_perm /
// row_half_mirror) lets GCNDPPCombine fold the mov_dpp into v_add_f32_dpp.
#define DPP_ADD(x, ctrl) \
  ((x) + __int_as_float(__builtin_amdgcn_update_dpp(0, __float_as_int(x), (ctrl), 0xf, 0xf, true)))

#define NSHARD 64
#define NEB 256   // edge-chunk blocks for the place pass
#define ECAP 6144 // fixed bucket stride in ebuf (mean fill 4096, sigma 64)

// ---------------- W-prep + single-pass bucket place ----------------

__global__ __launch_bounds__(256) void k_prep(const float* __restrict__ W0, const float* __restrict__ W1,
                                              const float* __restrict__ W2, const float* __restrict__ W3,
                                              const float* __restrict__ W4, const float* __restrict__ W5,
                                              unsigned short* __restrict__ wt,
                                              const int* __restrict__ esrc,
                                              const int* __restrict__ edst,
                                              int* __restrict__ bktcnt,
                                              int2* __restrict__ ebuf, int E, int N) {
  if (blockIdx.x < 384) {
    int gid = blockIdx.x * 256 + threadIdx.x; // 6 * 16384
    int m = gid >> 14;
    int r = gid & 16383;
    int k = r >> 8;
    int n = r & 255;
    const float* W = (m == 0) ? W0 : (m == 1) ? W1 : (m == 2) ? W2
                   : (m == 3) ? W3 : (m == 4) ? W4 : W5;
    wt[(size_t)m * 16384 + n * 64 + k] = f2bf(W[k * 256 + n]);
    return;
  }
  const int b = blockIdx.x - 384;
  const int nbk = (N + 255) >> 8;
  __shared__ int cnt[256], base[256];
  cnt[threadIdx.x] = 0;
  __syncthreads();
  const int chunk = (E + NEB - 1) / NEB;
  const int e0 = b * chunk, e1 = min(e0 + chunk, E);
  for (int e = e0 + threadIdx.x; e < e1; e += 256) atomicAdd(&cnt[edst[e] >> 8], 1);
  __syncthreads();
  if (threadIdx.x < nbk && cnt[threadIdx.x])
    base[threadIdx.x] = atomicAdd(&bktcnt[threadIdx.x], cnt[threadIdx.x]);
  cnt[threadIdx.x] = 0; // reuse as local cursor (own-index only before sync)
  __syncthreads();
  for (int e = e0 + threadIdx.x; e < e1; e += 256) {
    int d = edst[e];
    int bk = d >> 8;
    int p = base[bk] + atomicAdd(&cnt[bk], 1);
    ebuf[(size_t)bk * ECAP + p] = make_int2(d, esrc[e]);
  }
}

// ---------------- pass2 (y=2 of k_mm0): per-bucket CSR finalize, 4-padded ----------------
// Per-node lists padded to %4 (pad slots stay 0 from memset -> safe gather of row 0,
// masked by deg). rowptr packs pos|deg<<22. colb space reserved via global cursor.

static __device__ __forceinline__ void csr_pass2(const int2* __restrict__ ebuf,
                                                 const int* __restrict__ bktcnt,
                                                 int* __restrict__ rowptr,
                                                 int* __restrict__ colb,
                                                 int* __restrict__ ccur,
                                                 int N, char* smem) {
  const int b = blockIdx.x;
  const int nbk = (N + 255) >> 8;
  if (b >= nbk) return;
  int* hist = (int*)smem;          // 256
  int* s = (int*)smem + 256;       // 256 (scan buffer)
  int* sb = (int*)smem + 512;      // 1 (bucket colb-base broadcast)
  const int tid = threadIdx.x;
  const int lo = b * ECAP;
  const int hi = lo + bktcnt[b];
  hist[tid] = 0;
  __syncthreads();
  for (int i = lo + tid; i < hi; i += 256) atomicAdd(&hist[ebuf[i].x & 255], 1);
  __syncthreads();
  int deg = hist[tid];
  int pd = (deg + 3) & ~3;
  s[tid] = pd;
  __syncthreads();
  for (int off = 1; off < 256; off <<= 1) {
    int t = (tid >= off) ? s[tid - off] : 0;
    __syncthreads();
    s[tid] += t;
    __syncthreads();
  }
  if (tid == 255) sb[0] = atomicAdd(ccur, s[255]);
  __syncthreads();
  int pos = sb[0] + s[tid] - pd; // exclusive prefix of padded degrees
  int node = (b << 8) + tid;
  if (node < N) rowptr[node] = (int)((unsigned)pos | ((unsigned)deg << 22));
  hist[tid] = pos; // reuse as global cursor
  __syncthreads();
  for (int i = lo + tid; i < hi; i += 256) {
    int2 e = ebuf[i];
    int p = atomicAdd(&hist[e.x & 255], 1);
    colb[p] = e.y << 8; // byte offset into fp8 rows (256 fp8 = 256 B)
  }
}

// ---------------- MFMA dual GEMM + fused BN/GELU/residual producer (shared body) ----
// Gather copies (xlb/xrb) stored as OCP fp8 e4m3 (256 B/row) — consumed only by
// k_gat. Single-bf16 GEMM (outputs fp8-quantized anyway; hout keeps f32 quality).

static __device__ __forceinline__ void mm_gemm(const float* __restrict__ src,
                                               const float* __restrict__ bnsums,
                                               const float* __restrict__ g,
                                               const float* __restrict__ be,
                                               const float* __restrict__ resid,
                                               float* __restrict__ hout,
                                               const unsigned short* __restrict__ wt,
                                               unsigned char* __restrict__ xlb,
                                               unsigned char* __restrict__ xrb,
                                               int N, int ntiles, float inv_n,
                                               char* smem) {
  unsigned short* Bs = (unsigned short*)smem;           // 256*64 shorts, swizzled
  unsigned short* Ah = (unsigned short*)(smem + 32768); // 32*64
  const int t = threadIdx.x;
  const unsigned short* wb = wt + (blockIdx.y ? 16384 : 0);
  unsigned char* dst = blockIdx.y ? xrb : xlb;

  const int wave = t >> 6, lane = t & 63;
  const int rw = (wave & 1) * 16, cw = (wave >> 1) * 128;
  const int m15 = lane & 15, quad = lane >> 4;
  const int arow = t >> 3, ac0 = (t & 7) * 8;
  const int aoff = arow * 64 + (((t & 7) ^ (arow & 7)) << 3); // swizzled A slot

  float scale[8], shift[8];
  if (bnsums) {
    float* stat = (float*)smem; // overlay: consumed before Bs fill
    if (t < 128) {
      float a = 0.f;
#pragma unroll
      for (int sd = 0; sd < NSHARD; ++sd) a += bnsums[sd * 128 + t];
      stat[t] = a;
    }
    __syncthreads();
#pragma unroll
    for (int i = 0; i < 8; ++i) {
      int c = ac0 + i;
      float mu = stat[c] * inv_n;
      float var = stat[64 + c] * inv_n - mu * mu;
      float rs = rsqrtf(var + 1e-5f) * g[c];
      scale[i] = rs;
      shift[i] = be[c] - mu * rs;
    }
    __syncthreads(); // stat reads done before Bs fill overwrites
  }

#pragma unroll
  for (int j = 0; j < 8; ++j) {
    int cidx = t + 256 * j;
    int n = cidx >> 3, gg = cidx & 7;
    *(bf16x8*)&Bs[n * 64 + (((gg ^ ((n >> 3) & 7))) << 3)] =
        *(const bf16x8*)(wb + (size_t)n * 64 + gg * 8);
  }

  const bool wr_h = (hout != nullptr) && (blockIdx.y == 0);
  const int gstride = gridDim.x;

  float4 a0, a1, rv0, rv1;
  auto loadA = [&](int tl, float4& x0, float4& x1, float4& r0v, float4& r1v) {
    x0 = make_float4(0.f, 0.f, 0.f, 0.f);
    x1 = make_float4(0.f, 0.f, 0.f, 0.f);
    r0v = make_float4(0.f, 0.f, 0.f, 0.f);
    r1v = make_float4(0.f, 0.f, 0.f, 0.f);
    int gr = tl * 32 + arow;
    if (tl < ntiles && gr < N) {
      x0 = *(const float4*)(src + (size_t)gr * 64 + ac0);
      x1 = *(const float4*)(src + (size_t)gr * 64 + ac0 + 4);
      if (resid) {
        r0v = *(const float4*)(resid + (size_t)gr * 64 + ac0);
        r1v = *(const float4*)(resid + (size_t)gr * 64 + ac0 + 4);
      }
    }
  };
  loadA(blockIdx.x, a0, a1, rv0, rv1);

  for (int tile = blockIdx.x; tile < ntiles; tile += gstride) {
    int r0 = tile * 32;
    int gr = r0 + arow;
    {
      float vs[8] = {a0.x, a0.y, a0.z, a0.w, a1.x, a1.y, a1.z, a1.w};
      if (bnsums) {
        float rv[8] = {rv0.x, rv0.y, rv0.z, rv0.w, rv1.x, rv1.y, rv1.z, rv1.w};
#pragma unroll
        for (int i = 0; i < 8; ++i) {
          float v = fmaf(vs[i], scale[i], shift[i]);
          float ge = 0.5f * v * (1.f + erff(v * 0.70710678118654752f));
          vs[i] = ge + rv[i];
        }
        if (wr_h && gr < N) {
          float4 o0 = {vs[0], vs[1], vs[2], vs[3]};
          float4 o1 = {vs[4], vs[5], vs[6], vs[7]};
          *(float4*)(hout + (size_t)gr * 64 + ac0) = o0;
          *(float4*)(hout + (size_t)gr * 64 + ac0 + 4) = o1;
        }
      }
      bf16x8 hi8;
#pragma unroll
      for (int i = 0; i < 8; ++i) hi8[i] = (short)f2bf(vs[i]);
      *(bf16x8*)&Ah[aoff] = hi8;
    }
    __syncthreads();

    // software pipeline: issue next tile's A loads under MFMA + epilogue
    loadA(tile + gstride, a0, a1, rv0, rv1);

    f32x4 acc[8];
#pragma unroll
    for (int s = 0; s < 8; ++s) acc[s] = (f32x4){0.f, 0.f, 0.f, 0.f};
    const int xq = m15 & 7;
#pragma unroll
    for (int kk = 0; kk < 64; kk += 32) {
      const int ga = (((kk >> 3) + quad) ^ xq) << 3;
      bf16x8 ah = *(const bf16x8*)&Ah[(rw + m15) * 64 + ga];
#pragma unroll
      for (int s = 0; s < 8; ++s) {
        // B row cw + m15*8 + s -> acc[s] holds output column cw + m15*8 + s
        bf16x8 b = *(const bf16x8*)&Bs[(cw + m15 * 8 + s) * 64 + ga];
        acc[s] = __builtin_amdgcn_mfma_f32_16x16x32_bf16(ah, b, acc[s], 0, 0, 0);
      }
    }
#pragma unroll
    for (int r = 0; r < 4; ++r) {
      int row_g = r0 + rw + quad * 4 + r;
      if (row_g < N) {
        int w0 = __builtin_amdgcn_cvt_pk_fp8_f32(acc[0][r], acc[1][r], 0, false);
        w0 = __builtin_amdgcn_cvt_pk_fp8_f32(acc[2][r], acc[3][r], w0, true);
        int w1 = __builtin_amdgcn_cvt_pk_fp8_f32(acc[4][r], acc[5][r], 0, false);
        w1 = __builtin_amdgcn_cvt_pk_fp8_f32(acc[6][r], acc[7][r], w1, true);
        uint2 o = {(unsigned)w0, (unsigned)w1};
        *(uint2*)(dst + (size_t)row_g * 256 + cw + m15 * 8) = o;
      }
    }
    __syncthreads();
  }
}

__global__ __launch_bounds__(256, 4) void k_mm0(const float* __restrict__ src,
                                                const unsigned short* __restrict__ wt,
                                                unsigned char* __restrict__ xlb,
                                                unsigned char* __restrict__ xrb,
                                                const int2* __restrict__ ebuf,
                                                const int* __restrict__ bktcnt,
                                                int* __restrict__ rowptr,
                                                int* __restrict__ colb,
                                                int* __restrict__ ccur,
                                                int N, int ntiles) {
  __shared__ __align__(16) char smem[36864];
  if (blockIdx.y == 2) {
    csr_pass2(ebuf, bktcnt, rowptr, colb, ccur, N, smem);
    return;
  }
  mm_gemm(src, nullptr, nullptr, nullptr, nullptr, nullptr, wt, xlb, xrb, N, ntiles, 0.f, smem);
}

__global__ __launch_bounds__(256, 4) void k_mm1(const float* __restrict__ src,
                                                const float* __restrict__ bnsums,
                                                const float* __restrict__ g,
                                                const float* __restrict__ be,
                                                float* __restrict__ hout,
                                                const unsigned short* __restrict__ wt,
                                                unsigned char* __restrict__ xlb,
                                                unsigned char* __restrict__ xrb,
                                                int N, int ntiles, float inv_n) {
  __shared__ __align__(16) char smem[36864];
  mm_gemm(src, bnsums, g, be, nullptr, hout, wt, xlb, xrb, N, ntiles, inv_n, smem);
}

__global__ __launch_bounds__(256, 4) void k_mm2(const float* __restrict__ src,
                                                const float* __restrict__ bnsums,
                                                const float* __restrict__ g,
                                                const float* __restrict__ be,
                                                const float* __restrict__ resid,
                                                float* __restrict__ hout,
                                                const unsigned short* __restrict__ wt,
                                                unsigned char* __restrict__ xlb,
                                                unsigned char* __restrict__ xrb,
                                                int N, int ntiles, float inv_n) {
  __shared__ __align__(16) char smem[36864];
  mm_gemm(src, bnsums, g, be, resid, hout, wt, xlb, xrb, N, ntiles, inv_n, smem);
}

// ---------------- GATv2: 2-edges-per-wave, fp8 gather rows, f32 math ----
// Lanes 0-31 carry edge A, lanes 32-63 edge B (8 fp8 channels/lane, dwordx2
// gather serves both edges). Head = 8-lane group; score reduce = 3 DPP steps
// covering both edges at once. Per-channel arithmetic unchanged; all per-edge
// scalar-tail ops (DPP/exp/lsum/VMEM-issue) halve per edge.

static __device__ __forceinline__ void gat_body(const unsigned char* __restrict__ xlb,
                                                const unsigned char* __restrict__ xrb,
                                                const float* __restrict__ att,
                                                const float* __restrict__ bias,
                                                const int* __restrict__ rowptr,
                                                const int* __restrict__ colb,
                                                float* __restrict__ out,
                                                float* __restrict__ bnsums, int N) {
  __shared__ float sres[4][64];
  const int lane = threadIdx.x & 63;
  const int wv = threadIdx.x >> 6;
  const int half = lane >> 5; // which edge of the pair this lane serves
  const int l5 = lane & 31;
  const int node0 = blockIdx.x * 4 + wv;
  const bool valid = node0 < N;
  const int node = __builtin_amdgcn_readfirstlane(valid ? node0 : 0); // wave-uniform
  const int rp = rowptr[node];
  const int beg = rp & 0x3FFFFF;
  const int deg = (int)(((unsigned)rp) >> 22);
  const int end = valid ? beg + deg : beg;

  const unsigned char* xl = xlb; // wave-uniform base -> SADDR form
  const unsigned lb = (unsigned)l5 * 8u;

  auto sel = [&](int a, int b) { return (unsigned)(half ? b : a); };

  int4 c0 = *(const int4*)(colb + beg);     // edges 0..3 (16B-aligned: beg%4==0)
  int4 c1 = *(const int4*)(colb + beg + 4); // edges 4..7
  const unsigned self_off = (unsigned)(node << 8);
  uint2 vbs = *(const uint2*)(xl + self_off + lb);
  uint2 pd0 = *(const uint2*)(xl + (sel(c0.x, c0.y) + lb));
  uint2 pd1 = *(const uint2*)(xl + (sel(c0.z, c0.w) + lb));
  uint2 pt0 = *(const uint2*)(xl + (sel(c1.x, c1.y) + lb));
  uint2 pt1 = *(const uint2*)(xl + (sel(c1.z, c1.w) + lb));
  int4 cn = *(const int4*)(colb + beg + 8); // offsets for edges 8..11

  float4 aa = *(const float4*)(att + l5 * 8);
  float4 ab = *(const float4*)(att + l5 * 8 + 4);
  const float LOG2E = 1.4426950408889634f;
  const f32x2 a01 = {aa.x * LOG2E, aa.y * LOG2E};
  const f32x2 a23 = {aa.z * LOG2E, aa.w * LOG2E};
  const f32x2 a45 = {ab.x * LOG2E, ab.y * LOG2E};
  const f32x2 a67 = {ab.z * LOG2E, ab.w * LOG2E};
  const f32x2 c02 = {0.2f, 0.2f};
  uint2 xru = *(const uint2*)(xrb + self_off + lb);
  const f32x2 xr01 = __builtin_amdgcn_cvt_pk_f32_fp8((int)xru.x, false);
  const f32x2 xr23 = __builtin_amdgcn_cvt_pk_f32_fp8((int)xru.x, true);
  const f32x2 xr45 = __builtin_amdgcn_cvt_pk_f32_fp8((int)xru.y, false);
  const f32x2 xr67 = __builtin_amdgcn_cvt_pk_f32_fp8((int)xru.y, true);

  // score over 8 channels/lane, reduced across the 8-lane head group (both
  // halves reduce their own edge). Returns per-(head,edge) score; also yields
  // the converted channel values for the accumulation.
  auto score = [&](uint2 vb, f32x2& v01, f32x2& v23, f32x2& v45, f32x2& v67) -> float {
    v01 = __builtin_amdgcn_cvt_pk_f32_fp8((int)vb.x, false);
    v23 = __builtin_amdgcn_cvt_pk_f32_fp8((int)vb.x, true);
    v45 = __builtin_amdgcn_cvt_pk_f32_fp8((int)vb.y, false);
    v67 = __builtin_amdgcn_cvt_pk_f32_fp8((int)vb.y, true);
    f32x2 s01 = v01 + xr01;
    f32x2 s23 = v23 + xr23;
    f32x2 s45 = v45 + xr45;
    f32x2 s67 = v67 + xr67;
    s01 = __builtin_elementwise_max(s01, s01 * c02);
    s23 = __builtin_elementwise_max(s23, s23 * c02);
    s45 = __builtin_elementwise_max(s45, s45 * c02);
    s67 = __builtin_elementwise_max(s67, s67 * c02);
    f32x2 q = s01 * a01;
    q = __builtin_elementwise_fma(s23, a23, q);
    q = __builtin_elementwise_fma(s45, a45, q);
    q = __builtin_elementwise_fma(s67, a67, q);
    float p = q.x + q.y;
    p = DPP_ADD(p, 0xB1);  // quad_perm [1,0,3,2]
    p = DPP_ADD(p, 0x4E);  // quad_perm [2,3,0,1]
    p = DPP_ADD(p, 0x141); // row_half_mirror -> 8-lane (head) group sum
    return p;
  };

  f32x2 sv01, sv23, sv45, sv67;
  const float m = score(vbs, sv01, sv23, sv45, sv67); // self score (identical in both halves)

  const float hsel = half ? 0.f : 1.f; // self counted once (half 0)
  float lsum = hsel;
  const f32x2 hs2 = {hsel, hsel};
  f32x2 o01 = sv01 * hs2, o23 = sv23 * hs2, o45 = sv45 * hs2, o67 = sv67 * hs2;

  auto proc = [&](uint2 vb, int ebase) {
    f32x2 v01, v23, v45, v67;
    float p = score(vb, v01, v23, v45, v67);
    float w = __builtin_amdgcn_exp2f(fminf(p - m, 126.f));
    w = (ebase + half < end) ? w : 0.f;
    lsum += w;
    f32x2 w2 = {w, w};
    o01 = __builtin_elementwise_fma(w2, v01, o01);
    o23 = __builtin_elementwise_fma(w2, v23, o23);
    o45 = __builtin_elementwise_fma(w2, v45, o45);
    o67 = __builtin_elementwise_fma(w2, v67, o67);
  };

  for (int e = beg; e < end; e += 4) {
    uint2 pu0 = *(const uint2*)(xl + (sel(cn.x, cn.y) + lb));
    uint2 pu1 = *(const uint2*)(xl + (sel(cn.z, cn.w) + lb));
    cn = *(const int4*)(colb + e + 12);
    proc(pd0, e);
    proc(pd1, e + 2);
    pd0 = pt0; pd1 = pt1;
    pt0 = pu0; pt1 = pu1;
  }

  // per-(head) denominator: sum across the two edge-halves, then normalize
  lsum += __shfl_xor(lsum, 32, 64);
  float inv = __builtin_amdgcn_rcpf(lsum);
  float r[8] = {o01.x * inv, o01.y * inv, o23.x * inv, o23.y * inv,
                o45.x * inv, o45.y * inv, o67.x * inv, o67.y * inv};
#pragma unroll
  for (int j = 0; j < 8; ++j) {
    r[j] += __shfl_xor(r[j], 8, 64);  // head pairs
    r[j] += __shfl_xor(r[j], 16, 64); // all 4 heads
    r[j] += __shfl_xor(r[j], 32, 64); // edge halves
  }
  if (lane < 8) {
    float4 res0 = {0.f, 0.f, 0.f, 0.f}, res1 = {0.f, 0.f, 0.f, 0.f};
    if (valid) {
      float4 b0 = *(const float4*)(bias + lane * 8);
      float4 b1 = *(const float4*)(bias + lane * 8 + 4);
      res0.x = 0.25f * r[0] + b0.x;
      res0.y = 0.25f * r[1] + b0.y;
      res0.z = 0.25f * r[2] + b0.z;
      res0.w = 0.25f * r[3] + b0.w;
      res1.x = 0.25f * r[4] + b1.x;
      res1.y = 0.25f * r[5] + b1.y;
      res1.z = 0.25f * r[6] + b1.z;
      res1.w = 0.25f * r[7] + b1.w;
      *(float4*)(out + (size_t)node * 64 + lane * 8) = res0;
      *(float4*)(out + (size_t)node * 64 + lane * 8 + 4) = res1;
    }
    *(float4*)&sres[wv][lane * 8] = res0;
    *(float4*)&sres[wv][lane * 8 + 4] = res1;
  }
  __syncthreads();
  if (threadIdx.x < 64) {
    int c = threadIdx.x;
    float s0 = sres[0][c], s1 = sres[1][c], s2 = sres[2][c], s3 = sres[3][c];
    float* bs = bnsums + (size_t)(blockIdx.x & (NSHARD - 1)) * 128;
    atomicAdd(&bs[c], s0 + s1 + s2 + s3);
    atomicAdd(&bs[64 + c], s0 * s0 + s1 * s1 + s2 * s2 + s3 * s3);
  }
}

__global__ __launch_bounds__(256) void k_gat0(const unsigned char* __restrict__ xlb,
                                              const unsigned char* __restrict__ xrb,
                                              const float* __restrict__ att,
                                              const float* __restrict__ bias,
                                              const int* __restrict__ rowptr,
                                              const int* __restrict__ colb,
                                              float* __restrict__ out,
                                              float* __restrict__ bnsums, int N) {
  gat_body(xlb, xrb, att, bias, rowptr, colb, out, bnsums, N);
}
__global__ __launch_bounds__(256) void k_gat1(const unsigned char* __restrict__ xlb,
                                              const unsigned char* __restrict__ xrb,
                                              const float* __restrict__ att,
                                              const float* __restrict__ bias,
                                              const int* __restrict__ rowptr,
                                              const int* __restrict__ colb,
                                              float* __restrict__ out,
                                              float* __restrict__ bnsums, int N) {
  gat_body(xlb, xrb, att, bias, rowptr, colb, out, bnsums, N);
}
__global__ __launch_bounds__(256) void k_gat2(const unsigned char* __restrict__ xlb,
                                              const unsigned char* __restrict__ xrb,
                                              const float* __restrict__ att,
                                              const float* __restrict__ bias,
                                              const int* __restrict__ rowptr,
                                              const int* __restrict__ colb,
                                              float* __restrict__ out,
                                              float* __restrict__ bnsums, int N) {
  gat_body(xlb, xrb, att, bias, rowptr, colb, out, bnsums, N);
}

// ---------------- final: collapse shards -> BN+GELU+residual -> run-batched pool ----------------

__global__ __launch_bounds__(256) void k_bn_pool(const float* __restrict__ gat,
                                                 const float* __restrict__ bnsums,
                                                 const float* __restrict__ g,
                                                 const float* __restrict__ be,
                                                 const float* __restrict__ resid,
                                                 const int* __restrict__ batch,
                                                 float* __restrict__ pool,
                                                 int N, float inv_n) {
  __shared__ float sc[64], sh[64];
  if (threadIdx.x < 64) {
    int c = threadIdx.x;
    float s = 0.f, q = 0.f;
    for (int sd = 0; sd < NSHARD; ++sd) {
      s += bnsums[sd * 128 + c];
      q += bnsums[sd * 128 + 64 + c];
    }
    float mu = s * inv_n;
    float var = q * inv_n - mu * mu;
    float rs = rsqrtf(var + 1e-5f) * g[c];
    sc[c] = rs;
    sh[c] = be[c] - mu * rs;
  }
  __syncthreads();
  const int c = threadIdx.x & 63;
  const int wv = threadIdx.x >> 6;
  int n0 = (blockIdx.x * 4 + wv) * 32;
  if (n0 >= N) return;
  int n1 = min(n0 + 32, N);
  int curg = batch[n0]; // wave-uniform (batch sorted)
  float acc = 0.f;
  for (int n = n0; n < n1; ++n) {
    int b = batch[n];
    if (b != curg) {
      atomicAdd(&pool[(size_t)curg * 64 + c], acc);
      acc = 0.f;
      curg = b;
    }
    float v = fmaf(gat[(size_t)n * 64 + c], sc[c], sh[c]);
    float ge = 0.5f * v * (1.f + erff(v * 0.70710678118654752f));
    acc += ge + resid[(size_t)n * 64 + c];
  }
  atomicAdd(&pool[(size_t)curg * 64 + c], acc);
}

// ---------------- heads ----------------

__global__ void k_head(const float* __restrict__ pool, const float* __restrict__ Wmu,
                       const float* __restrict__ bmu, const float* __restrict__ Wlv,
                       const float* __restrict__ blv, float* __restrict__ out, int G) {
  int g = blockIdx.x;
  int c = threadIdx.x; // 64 threads
  __shared__ float row[64];
  row[c] = pool[(size_t)g * 64 + c];
  __syncthreads();
  float am = 0.f, al = 0.f;
  for (int k = 0; k < 64; ++k) {
    float r = row[k];
    am = fmaf(r, Wmu[k * 64 + c], am);
    al = fmaf(r, Wlv[k * 64 + c], al);
  }
  out[(size_t)g * 64 + c] = am + bmu[c];
  out[(size_t)G * 64 + (size_t)g * 64 + c] = al + blv[c];
}

// ---------------- launch ----------------

extern "C" void kernel_launch(void* const* d_in, const int* in_sizes, int n_in,
                              void* d_out, int out_size, void* d_ws, size_t ws_size,
                              hipStream_t stream) {
  const float* x    = (const float*)d_in[0];
  const int* esrc   = (const int*)d_in[1];
  const int* edst   = (const int*)d_in[2];
  const int* batch  = (const int*)d_in[3];
  const float* Wl[3]  = {(const float*)d_in[5],  (const float*)d_in[11], (const float*)d_in[17]};
  const float* Wr[3]  = {(const float*)d_in[6],  (const float*)d_in[12], (const float*)d_in[18]};
  const float* att[3] = {(const float*)d_in[7],  (const float*)d_in[13], (const float*)d_in[19]};
  const float* bia[3] = {(const float*)d_in[8],  (const float*)d_in[14], (const float*)d_in[20]};
  const float* gam[3] = {(const float*)d_in[9],  (const float*)d_in[15], (const float*)d_in[21]};
  const float* bet[3] = {(const float*)d_in[10], (const float*)d_in[16], (const float*)d_in[22]};
  const float* Wmu = (const float*)d_in[23];
  const float* bmu = (const float*)d_in[24];
  const float* Wlv = (const float*)d_in[25];
  const float* blv = (const float*)d_in[26];
  float* out = (float*)d_out;

  const int N = in_sizes[0] / 64;
  const int E = in_sizes[1];
  const int G = out_size / 128;
  const int nbk = (N + 255) / 256;

  char* p = (char*)d_ws;
  auto alloc = [&](size_t bytes) -> void* {
    void* r = (void*)p;
    p += (bytes + 255) & ~(size_t)255;
    return r;
  };
  // zero-init region first (one memset: bktcnt + bnsums + pool + ccur + colb)
  int*   bktcnt  = (int*)alloc(256 * 4);
  float* bnsums  = (float*)alloc(3 * NSHARD * 128 * 4);
  float* pool    = (float*)alloc((size_t)G * 64 * 4);
  int*   ccur    = (int*)alloc(256);
  int*   colb    = (int*)alloc(((size_t)E + 3 * (size_t)N + 64) * 4); // 4-padded rows + zero tail
  char*  zend    = p;
  unsigned char* xlb = (unsigned char*)alloc((size_t)N * 256);
  unsigned char* xrb = (unsigned char*)alloc((size_t)N * 256);
  float* hA     = (float*)alloc((size_t)N * 64 * 4);
  float* hB     = (float*)alloc((size_t)N * 64 * 4);
  float* gat    = (float*)alloc((size_t)N * 64 * 4);
  int*   rowptr = (int*)alloc((size_t)(N + 1) * 4);
  int2*  ebuf   = (int2*)alloc((size_t)nbk * ECAP * 8);
  unsigned short* wt = (unsigned short*)alloc(6 * 16384 * 2);

  const int nbGat = (N + 3) / 4;
  const int ntiles = (N + 31) / 32;
  const float inv_n = 1.f / (float)N;

  hipMemsetAsync(bktcnt, 0, (size_t)(zend - (char*)bktcnt), stream);

  // ---- CSR build: W-prep + single-pass bucket place (fused) ----
  k_prep<<<384 + NEB, 256, 0, stream>>>(Wl[0], Wr[0], Wl[1], Wr[1], Wl[2], Wr[2], wt,
                                        esrc, edst, bktcnt, ebuf, E, N);

  float* bns0 = bnsums;
  float* bns1 = bnsums + NSHARD * 128;
  float* bns2 = bnsums + 2 * NSHARD * 128;

  // ---- layer 0 (y=2 partition finalizes CSR concurrently with the GEMM) ----
  k_mm0<<<dim3(512, 3), 256, 0, stream>>>(x, wt, xlb, xrb, ebuf, bktcnt, rowptr, colb,
                                          ccur, N, ntiles);
  k_gat0<<<nbGat, 256, 0, stream>>>(xlb, xrb, att[0], bia[0], rowptr, colb, gat, bns0, N);
  // ---- layer 1 (applies h0 = gelu(bn0(gat0))) ----
  k_mm1<<<dim3(512, 2), 256, 0, stream>>>(gat, bns0, gam[0], bet[0], hA,
                                          wt + 2 * 16384, xlb, xrb, N, ntiles, inv_n);
  k_gat1<<<nbGat, 256, 0, stream>>>(xlb, xrb, att[1], bia[1], rowptr, colb, gat, bns1, N);
  // ---- layer 2 (applies h1 = gelu(bn1(gat1)) + h0) ----
  k_mm2<<<dim3(512, 2), 256, 0, stream>>>(gat, bns1, gam[1], bet[1], hA, hB,
                                          wt + 4 * 16384, xlb, xrb, N, ntiles, inv_n);
  k_gat2<<<nbGat, 256, 0, stream>>>(xlb, xrb, att[2], bia[2], rowptr, colb, gat, bns2, N);
  // ---- final: h2 = gelu(bn2(gat2)) + h1 -> pool ----
  k_bn_pool<<<(N + 127) / 128, 256, 0, stream>>>(gat, bns2, gam[2], bet[2], hB, batch, pool,
                                                 N, inv_n);
  k_head<<<G, 64, 0, stream>>>(pool, Wmu, bmu, Wlv, blv, out, G);
}